// Round 5
// baseline (1592.932 us; speedup 1.0000x reference)
//
#include <hip/hip_runtime.h>

#define DD 64
#define GG 64
#define EPSV 1e-5f
#define SLOPE 0.01f

#define AG_WAVES 8
#define AG_NPW 8
#define AG_NODES (AG_WAVES*AG_NPW) // 64 nodes per block
#define NRM_NPW 16
#define NPART 8                    // XCD count on MI355X

// ----------------- CSR build (XCD-partitioned scatter) -----------------
__global__ void deg_kernel(const int* __restrict__ src, const int* __restrict__ dst,
                           int* __restrict__ deg_f, int* __restrict__ deg_b,
                           int E, int npp) {
  int part = blockIdx.x & (NPART-1);
  int lo = part*npp, hi = lo+npp;
  int tid = (blockIdx.x >> 3)*blockDim.x + threadIdx.x;
  int stride = (gridDim.x >> 3)*blockDim.x;
  for (int e=tid; e<E; e+=stride) {
    int d = dst[e], s = src[e];
    if (d >= lo && d < hi) atomicAdd(&deg_f[d], 1);
    if (s >= lo && s < hi) atomicAdd(&deg_b[s], 1);
  }
}

__global__ void fill_kernel(const int* __restrict__ src, const int* __restrict__ dst,
                            int* __restrict__ cur_f, int* __restrict__ cur_b,
                            int* __restrict__ col_f, int* __restrict__ col_b,
                            int E, int npp) {
  int part = blockIdx.x & (NPART-1);
  int lo = part*npp, hi = lo+npp;
  int tid = (blockIdx.x >> 3)*blockDim.x + threadIdx.x;
  int stride = (gridDim.x >> 3)*blockDim.x;
  for (int e=tid; e<E; e+=stride) {
    int s = src[e], d = dst[e];
    if (d >= lo && d < hi) { int p = atomicAdd(&cur_f[d], 1); col_f[p] = s; }
    if (s >= lo && s < hi) { int q = atomicAdd(&cur_b[s], 1); col_b[q] = d; }
  }
}

// ----------------- fused scan over concatenated [deg_f | deg_b] (2N) -----------------
__global__ void block_sum_kernel(const int* __restrict__ v, int* __restrict__ partial, int M) {
  __shared__ int sm[1024];
  int i = blockIdx.x*1024 + threadIdx.x;
  sm[threadIdx.x] = (i<M) ? v[i] : 0;
  __syncthreads();
  for (int s=512; s>0; s>>=1) {
    if (threadIdx.x < s) sm[threadIdx.x] += sm[threadIdx.x+s];
    __syncthreads();
  }
  if (threadIdx.x==0) partial[blockIdx.x] = sm[0];
}

__global__ void scan_partial_kernel(int* __restrict__ partial, int nb) {
  __shared__ int sm[256];
  int t = threadIdx.x;
  int v = (t<nb) ? partial[t] : 0;
  int orig = v;
  sm[t] = v; __syncthreads();
  for (int off=1; off<256; off<<=1) {
    int a = (t>=off) ? sm[t-off] : 0;
    __syncthreads();
    v += a; sm[t] = v;
    __syncthreads();
  }
  if (t<nb) partial[t] = v - orig;   // exclusive block offsets
}

__global__ void block_scan_kernel(const int* __restrict__ deg, const int* __restrict__ partial,
                                  int* __restrict__ rp_f, int* __restrict__ rp_b,
                                  int* __restrict__ cur_f, int* __restrict__ cur_b,
                                  int N, int E) {
  __shared__ int sm[1024];
  int i = blockIdx.x*1024 + threadIdx.x;
  int v = (i<2*N) ? deg[i] : 0;
  int orig = v;
  sm[threadIdx.x] = v; __syncthreads();
  for (int off=1; off<1024; off<<=1) {
    int a = (threadIdx.x>=off) ? sm[threadIdx.x-off] : 0;
    __syncthreads();
    v += a; sm[threadIdx.x] = v;
    __syncthreads();
  }
  int excl = v - orig + partial[blockIdx.x];
  if (i < N)        { rp_f[i] = excl;     cur_f[i] = excl; }
  else if (i < 2*N) { rp_b[i-N] = excl-E; cur_b[i-N] = excl-E; }  // sum(deg_f)==E
  if (blockIdx.x==0 && threadIdx.x==0) { rp_f[N] = E; rp_b[N] = E; }
}

__global__ void cnt_kernel(const int* __restrict__ batch, int* __restrict__ cnt, int N) {
  __shared__ int hist[GG];
  if (threadIdx.x < GG) hist[threadIdx.x] = 0;
  __syncthreads();
  int i = blockIdx.x*blockDim.x + threadIdx.x;
  int stride = gridDim.x*blockDim.x;
  for (int n=i; n<N; n+=stride) atomicAdd(&hist[batch[n]], 1);
  __syncthreads();
  if (threadIdx.x < GG) atomicAdd(&cnt[threadIdx.x], hist[threadIdx.x]);
}

// ----------------- fused mean-agg (both dirs) + dual GEMM + graph-sum -----------------
// No __syncthreads: each wave owns srow/hrow rows [wid*8 .. wid*8+7].
// Weights read straight from global (32KB total -> L1-resident, shared by all blocks).
// LDS = 32KB/block -> 4 blocks/CU -> up to 32 waves/CU.
__global__ __launch_bounds__(512) void agg_gemm_kernel(
    const float* __restrict__ hin,
    const float* __restrict__ Wl, const float* __restrict__ Wr, const float* __restrict__ bias,
    const int* __restrict__ rp_f, const int* __restrict__ col_f,
    const int* __restrict__ rp_b, const int* __restrict__ col_b,
    const int* __restrict__ batch,
    float* __restrict__ t, float* __restrict__ gsum, int N)
{
  __shared__ float srow[AG_NODES][DD];
  __shared__ float hrow[AG_NODES][DD];

  int wid = threadIdx.x >> 6;
  int lane = threadIdx.x & 63;
  int nodeBase = blockIdx.x*AG_NODES + wid*AG_NPW;
  const float* hl = hin + lane;        // per-lane feature column base

  for (int nn=0; nn<AG_NPW; ++nn) {
    int node = nodeBase + nn;
    float sval = 0.f, hval = 0.f;
    if (node < N) {
      int s0 = rp_f[node], e0 = rp_f[node+1];
      float accf = 0.f;
      for (int base=s0; base<e0; base+=64) {
        int m = e0-base; if (m>64) m=64;
        int jv = (lane<m) ? col_f[base+lane] : 0;
        float a0=0.f,a1=0.f,a2=0.f,a3=0.f,a4=0.f,a5=0.f,a6=0.f,a7=0.f;
        int q=0;
        for (; q+7<m; q+=8) {
          int j0=__shfl(jv,q),  j1=__shfl(jv,q+1);
          int j2=__shfl(jv,q+2),j3=__shfl(jv,q+3);
          int j4=__shfl(jv,q+4),j5=__shfl(jv,q+5);
          int j6=__shfl(jv,q+6),j7=__shfl(jv,q+7);
          a0 += hl[(size_t)j0*DD]; a1 += hl[(size_t)j1*DD];
          a2 += hl[(size_t)j2*DD]; a3 += hl[(size_t)j3*DD];
          a4 += hl[(size_t)j4*DD]; a5 += hl[(size_t)j5*DD];
          a6 += hl[(size_t)j6*DD]; a7 += hl[(size_t)j7*DD];
        }
        for (; q<m; ++q) { int j=__shfl(jv,q); a0 += hl[(size_t)j*DD]; }
        accf += ((a0+a1)+(a2+a3)) + ((a4+a5)+(a6+a7));
      }
      int s1 = rp_b[node], e1 = rp_b[node+1];
      float accb = 0.f;
      for (int base=s1; base<e1; base+=64) {
        int m = e1-base; if (m>64) m=64;
        int jv = (lane<m) ? col_b[base+lane] : 0;
        float a0=0.f,a1=0.f,a2=0.f,a3=0.f,a4=0.f,a5=0.f,a6=0.f,a7=0.f;
        int q=0;
        for (; q+7<m; q+=8) {
          int j0=__shfl(jv,q),  j1=__shfl(jv,q+1);
          int j2=__shfl(jv,q+2),j3=__shfl(jv,q+3);
          int j4=__shfl(jv,q+4),j5=__shfl(jv,q+5);
          int j6=__shfl(jv,q+6),j7=__shfl(jv,q+7);
          a0 += hl[(size_t)j0*DD]; a1 += hl[(size_t)j1*DD];
          a2 += hl[(size_t)j2*DD]; a3 += hl[(size_t)j3*DD];
          a4 += hl[(size_t)j4*DD]; a5 += hl[(size_t)j5*DD];
          a6 += hl[(size_t)j6*DD]; a7 += hl[(size_t)j7*DD];
        }
        for (; q<m; ++q) { int j=__shfl(jv,q); a0 += hl[(size_t)j*DD]; }
        accb += ((a0+a1)+(a2+a3)) + ((a4+a5)+(a6+a7));
      }
      float df = fmaxf((float)(e0-s0), 1.f);
      float db = fmaxf((float)(e1-s1), 1.f);
      sval = 0.5f*(accf/df + accb/db);   // fold the 0.5 here
      hval = hin[(size_t)node*DD+lane];
    }
    srow[wid*AG_NPW+nn][lane] = sval;
    hrow[wid*AG_NPW+nn][lane] = hval;
  }
  // no barrier needed: this wave wrote and will read only its own 8 rows

  float bv = bias[lane];
  float tacc[AG_NPW];
  #pragma unroll
  for (int nn=0; nn<AG_NPW; ++nn) tacc[nn]=bv;

  for (int k=0; k<DD; k+=4) {
    float w0 = Wl[(k+0)*DD+lane], w1 = Wl[(k+1)*DD+lane];
    float w2 = Wl[(k+2)*DD+lane], w3 = Wl[(k+3)*DD+lane];
    float r0 = Wr[(k+0)*DD+lane], r1 = Wr[(k+1)*DD+lane];
    float r2 = Wr[(k+2)*DD+lane], r3 = Wr[(k+3)*DD+lane];
    #pragma unroll
    for (int nn=0; nn<AG_NPW; ++nn) {
      float4 sv = *(const float4*)&srow[wid*AG_NPW+nn][k];
      float4 hv = *(const float4*)&hrow[wid*AG_NPW+nn][k];
      tacc[nn] += sv.x*w0 + sv.y*w1 + sv.z*w2 + sv.w*w3
                + hv.x*r0 + hv.y*r1 + hv.z*r2 + hv.w*r3;
    }
  }

  // write t + per-graph accumulate (batch is sorted -> few flushes)
  int gcur = -1; float gacc = 0.f;
  for (int nn=0; nn<AG_NPW; ++nn) {
    int node = nodeBase+nn;
    if (node >= N) break;
    t[(size_t)node*DD+lane] = tacc[nn];
    int g = batch[node];
    if (g != gcur) {
      if (gcur >= 0) atomicAdd(&gsum[gcur*DD+lane], gacc);
      gcur = g; gacc = 0.f;
    }
    gacc += tacc[nn];
  }
  if (gcur >= 0) atomicAdd(&gsum[gcur*DD+lane], gacc);
}

// ----------------- GraphNorm pass 1 -----------------
__global__ void norm1_kernel(float* __restrict__ t, const float* __restrict__ gsum,
                             const int* __restrict__ cnt, const int* __restrict__ batch,
                             const float* __restrict__ gms, float* __restrict__ vsum, int N)
{
  int wid = (blockIdx.x*blockDim.x + threadIdx.x) >> 6;
  int lane = threadIdx.x & 63;
  int base = wid*NRM_NPW;
  if (base >= N) return;
  float msv = gms[lane];
  int gcur = -1; float mean = 0.f; float vacc = 0.f;
  int end = base+NRM_NPW; if (end>N) end=N;
  for (int node=base; node<end; ++node) {
    int g = batch[node];
    if (g != gcur) {
      if (gcur>=0) atomicAdd(&vsum[gcur*DD+lane], vacc);
      vacc = 0.f;
      float invc = 1.f / fmaxf((float)cnt[g], 1.f);
      mean = gsum[g*DD+lane]*invc;
      gcur = g;
    }
    float u = t[(size_t)node*DD+lane] - msv*mean;
    t[(size_t)node*DD+lane] = u;
    vacc += u*u;
  }
  if (gcur>=0) atomicAdd(&vsum[gcur*DD+lane], vacc);
}

// ----------------- GraphNorm pass 2 -----------------
__global__ void norm2_kernel(const float* __restrict__ t, const float* __restrict__ vsum,
                             const int* __restrict__ cnt, const int* __restrict__ batch,
                             const float* __restrict__ gw, const float* __restrict__ gb,
                             float* __restrict__ h, int resid, int N)
{
  int wid = (blockIdx.x*blockDim.x + threadIdx.x) >> 6;
  int lane = threadIdx.x & 63;
  int base = wid*NRM_NPW;
  if (base >= N) return;
  float wv = gw[lane], bv = gb[lane];
  int gcur=-1; float rs=0.f;
  int end = base+NRM_NPW; if (end>N) end=N;
  for (int node=base; node<end; ++node) {
    int g = batch[node];
    if (g!=gcur) {
      float invc = 1.f/fmaxf((float)cnt[g],1.f);
      rs = rsqrtf(vsum[g*DD+lane]*invc + EPSV);
      gcur=g;
    }
    float u = t[(size_t)node*DD+lane];
    float y = wv*u*rs + bv;
    y = (y>=0.f) ? y : SLOPE*y;
    float hv = resid ? (h[(size_t)node*DD+lane] + y) : y;
    h[(size_t)node*DD+lane] = hv;
  }
}

// ----------------- global mean pool -----------------
__global__ void pool_kernel(const float* __restrict__ h, const int* __restrict__ batch,
                            float* __restrict__ pout, int N)
{
  int wid = (blockIdx.x*blockDim.x + threadIdx.x) >> 6;
  int lane = threadIdx.x & 63;
  int base = wid*NRM_NPW;
  if (base>=N) return;
  int gcur=-1; float acc=0.f;
  int end=base+NRM_NPW; if (end>N) end=N;
  for (int node=base; node<end; ++node) {
    int g = batch[node];
    if (g!=gcur) { if (gcur>=0) atomicAdd(&pout[gcur*DD+lane],acc); acc=0.f; gcur=g; }
    acc += h[(size_t)node*DD+lane];
  }
  if (gcur>=0) atomicAdd(&pout[gcur*DD+lane],acc);
}

__global__ void finalize_kernel(const float* __restrict__ pout, const int* __restrict__ cnt,
                                float* __restrict__ out)
{
  int i = blockIdx.x*blockDim.x + threadIdx.x;
  if (i < GG*DD) {
    float invc = 1.f/fmaxf((float)cnt[i>>6],1.f);
    out[i] = pout[i]*invc;
  }
}

extern "C" void kernel_launch(void* const* d_in, const int* in_sizes, int n_in,
                              void* d_out, int out_size, void* d_ws, size_t ws_size,
                              hipStream_t stream)
{
  const float* x    = (const float*)d_in[0];
  const int*  ei    = (const int*)d_in[1];
  const int*  batch = (const int*)d_in[2];
  const float* W_l  = (const float*)d_in[3];
  const float* W_r  = (const float*)d_in[4];
  const float* bias = (const float*)d_in[5];
  const float* gn_w = (const float*)d_in[6];
  const float* gn_b = (const float*)d_in[7];
  const float* gn_ms= (const float*)d_in[8];

  int N = in_sizes[2];
  int E = in_sizes[1]/2;
  int L = in_sizes[5]/DD;
  const int* src = ei;
  const int* dst = ei + E;

  // ---- workspace layout: zero-zone first (single memset) ----
  char* p = (char*)d_ws;
  int*   deg   = (int*)p;   p += (size_t)2*N*4;        // [deg_f | deg_b]
  int*   cnt   = (int*)p;   p += GG*4;
  float* gsum  = (float*)p; p += (size_t)L*GG*DD*4;    // per-layer
  float* vsum  = (float*)p; p += (size_t)L*GG*DD*4;    // per-layer
  float* pout  = (float*)p; p += GG*DD*4;
  size_t zeroBytes = (char*)p - (char*)d_ws;

  float* h     = (float*)p; p += (size_t)N*DD*4;
  float* t     = (float*)p; p += (size_t)N*DD*4;
  int* rp_f    = (int*)p; p += (size_t)(N+1)*4;
  int* rp_b    = (int*)p; p += (size_t)(N+1)*4;
  int* cur_f   = (int*)p; p += (size_t)N*4;
  int* cur_b   = (int*)p; p += (size_t)N*4;
  int* col_f   = (int*)p; p += (size_t)E*4;
  int* col_b   = (int*)p; p += (size_t)E*4;
  int* partial = (int*)p; p += 256*4;

  int* deg_f = deg;
  int* deg_b = deg + N;

  hipMemsetAsync(d_ws, 0, zeroBytes, stream);

  int npp = (N + NPART-1)/NPART;
  int eg = 2048;                       // multiple of NPART
  deg_kernel<<<eg, 256, 0, stream>>>(src, dst, deg_f, deg_b, E, npp);
  cnt_kernel<<<391, 256, 0, stream>>>(batch, cnt, N);

  int nb2 = (2*N + 1023)/1024;         // <= 256
  block_sum_kernel<<<nb2, 1024, 0, stream>>>(deg, partial, 2*N);
  scan_partial_kernel<<<1, 256, 0, stream>>>(partial, nb2);
  block_scan_kernel<<<nb2, 1024, 0, stream>>>(deg, partial, rp_f, rp_b, cur_f, cur_b, N, E);

  fill_kernel<<<eg, 256, 0, stream>>>(src, dst, cur_f, cur_b, col_f, col_b, E, npp);

  int agBlocks = (N + AG_NODES-1)/AG_NODES;
  int nrmWaves = (N + NRM_NPW-1)/NRM_NPW;
  int nrmBlocks = (nrmWaves+3)/4;

  for (int i=0; i<L; ++i) {
    const float* hin = (i==0) ? x : h;
    float* gsum_i = gsum + (size_t)i*GG*DD;
    float* vsum_i = vsum + (size_t)i*GG*DD;
    agg_gemm_kernel<<<agBlocks, 512, 0, stream>>>(hin, W_l+(size_t)i*DD*DD, W_r+(size_t)i*DD*DD,
                                                  bias+(size_t)i*DD,
                                                  rp_f, col_f, rp_b, col_b, batch, t, gsum_i, N);
    norm1_kernel<<<nrmBlocks, 256, 0, stream>>>(t, gsum_i, cnt, batch, gn_ms+(size_t)i*DD, vsum_i, N);
    norm2_kernel<<<nrmBlocks, 256, 0, stream>>>(t, vsum_i, cnt, batch, gn_w+(size_t)i*DD,
                                                gn_b+(size_t)i*DD, h, (i>=2)?1:0, N);
  }
  pool_kernel<<<nrmBlocks, 256, 0, stream>>>(h, batch, pout, N);
  finalize_kernel<<<16, 256, 0, stream>>>(pout, cnt, (float*)d_out);
}

// Round 6
// 1558.485 us; speedup vs baseline: 1.0221x; 1.0221x over previous
//
#include <hip/hip_runtime.h>

#define DD 64
#define GG 64
#define EPSV 1e-5f
#define SLOPE 0.01f

#define AG_WAVES 8
#define AG_NPW 8
#define AG_NODES (AG_WAVES*AG_NPW) // 64 nodes per block
#define NRM_NPW 16
#define NPART 8                    // XCD count on MI355X

typedef unsigned short ushort_t;
typedef unsigned int uint_t;

__device__ __forceinline__ ushort_t f2bf(float f) {
  uint_t u = __float_as_uint(f);
  uint_t r = (u + 0x7fffu + ((u >> 16) & 1u)) >> 16;   // round-to-nearest-even
  return (ushort_t)r;
}
__device__ __forceinline__ float bf2f(ushort_t s) {
  return __uint_as_float(((uint_t)s) << 16);
}

// ----------------- CSR build (XCD-partitioned scatter) -----------------
__global__ void deg_kernel(const int* __restrict__ src, const int* __restrict__ dst,
                           int* __restrict__ deg_f, int* __restrict__ deg_b,
                           int E, int npp) {
  int part = blockIdx.x & (NPART-1);
  int lo = part*npp, hi = lo+npp;
  int tid = (blockIdx.x >> 3)*blockDim.x + threadIdx.x;
  int stride = (gridDim.x >> 3)*blockDim.x;
  for (int e=tid; e<E; e+=stride) {
    int d = dst[e], s = src[e];
    if (d >= lo && d < hi) atomicAdd(&deg_f[d], 1);
    if (s >= lo && s < hi) atomicAdd(&deg_b[s], 1);
  }
}

__global__ void fill_kernel(const int* __restrict__ src, const int* __restrict__ dst,
                            int* __restrict__ cur_f, int* __restrict__ cur_b,
                            int* __restrict__ col_f, int* __restrict__ col_b,
                            int E, int npp) {
  int part = blockIdx.x & (NPART-1);
  int lo = part*npp, hi = lo+npp;
  int tid = (blockIdx.x >> 3)*blockDim.x + threadIdx.x;
  int stride = (gridDim.x >> 3)*blockDim.x;
  for (int e=tid; e<E; e+=stride) {
    int s = src[e], d = dst[e];
    if (d >= lo && d < hi) { int p = atomicAdd(&cur_f[d], 1); col_f[p] = s; }
    if (s >= lo && s < hi) { int q = atomicAdd(&cur_b[s], 1); col_b[q] = d; }
  }
}

// ----------------- fused scan over concatenated [deg_f | deg_b] (2N) -----------------
__global__ void block_sum_kernel(const int* __restrict__ v, int* __restrict__ partial, int M) {
  __shared__ int sm[1024];
  int i = blockIdx.x*1024 + threadIdx.x;
  sm[threadIdx.x] = (i<M) ? v[i] : 0;
  __syncthreads();
  for (int s=512; s>0; s>>=1) {
    if (threadIdx.x < s) sm[threadIdx.x] += sm[threadIdx.x+s];
    __syncthreads();
  }
  if (threadIdx.x==0) partial[blockIdx.x] = sm[0];
}

__global__ void scan_partial_kernel(int* __restrict__ partial, int nb) {
  __shared__ int sm[256];
  int t = threadIdx.x;
  int v = (t<nb) ? partial[t] : 0;
  int orig = v;
  sm[t] = v; __syncthreads();
  for (int off=1; off<256; off<<=1) {
    int a = (t>=off) ? sm[t-off] : 0;
    __syncthreads();
    v += a; sm[t] = v;
    __syncthreads();
  }
  if (t<nb) partial[t] = v - orig;   // exclusive block offsets
}

__global__ void block_scan_kernel(const int* __restrict__ deg, const int* __restrict__ partial,
                                  int* __restrict__ rp_f, int* __restrict__ rp_b,
                                  int* __restrict__ cur_f, int* __restrict__ cur_b,
                                  int N, int E) {
  __shared__ int sm[1024];
  int i = blockIdx.x*1024 + threadIdx.x;
  int v = (i<2*N) ? deg[i] : 0;
  int orig = v;
  sm[threadIdx.x] = v; __syncthreads();
  for (int off=1; off<1024; off<<=1) {
    int a = (threadIdx.x>=off) ? sm[threadIdx.x-off] : 0;
    __syncthreads();
    v += a; sm[threadIdx.x] = v;
    __syncthreads();
  }
  int excl = v - orig + partial[blockIdx.x];
  if (i < N)        { rp_f[i] = excl;     cur_f[i] = excl; }
  else if (i < 2*N) { rp_b[i-N] = excl-E; cur_b[i-N] = excl-E; }  // sum(deg_f)==E
  if (blockIdx.x==0 && threadIdx.x==0) { rp_f[N] = E; rp_b[N] = E; }
}

__global__ void cnt_kernel(const int* __restrict__ batch, int* __restrict__ cnt, int N) {
  __shared__ int hist[GG];
  if (threadIdx.x < GG) hist[threadIdx.x] = 0;
  __syncthreads();
  int i = blockIdx.x*blockDim.x + threadIdx.x;
  int stride = gridDim.x*blockDim.x;
  for (int n=i; n<N; n+=stride) atomicAdd(&hist[batch[n]], 1);
  __syncthreads();
  if (threadIdx.x < GG) atomicAdd(&cnt[threadIdx.x], hist[threadIdx.x]);
}

// ----------------- fp32 -> bf16 shadow -----------------
__global__ void tobf16_kernel(const float* __restrict__ in, ushort_t* __restrict__ out, int M) {
  int i = blockIdx.x*blockDim.x + threadIdx.x;
  int stride = gridDim.x*blockDim.x;
  for (int k=i; k<M; k+=stride) out[k] = f2bf(in[k]);
}

// ----------------- fused mean-agg (both dirs, bf16 gather) + dual GEMM + graph-sum -----------------
// No __syncthreads: each wave owns srow/hrow rows [wid*8 .. wid*8+7].
// Neighbor rows gathered from the bf16 shadow (128 B/row); root + GEMM stay fp32.
__global__ __launch_bounds__(512) void agg_gemm_kernel(
    const float* __restrict__ hin, const ushort_t* __restrict__ hb,
    const float* __restrict__ Wl, const float* __restrict__ Wr, const float* __restrict__ bias,
    const int* __restrict__ rp_f, const int* __restrict__ col_f,
    const int* __restrict__ rp_b, const int* __restrict__ col_b,
    const int* __restrict__ batch,
    float* __restrict__ t, float* __restrict__ gsum, int N)
{
  __shared__ float srow[AG_NODES][DD];
  __shared__ float hrow[AG_NODES][DD];

  int wid = threadIdx.x >> 6;
  int lane = threadIdx.x & 63;
  int nodeBase = blockIdx.x*AG_NODES + wid*AG_NPW;
  const ushort_t* hbl = hb + lane;     // per-lane bf16 feature column base

  for (int nn=0; nn<AG_NPW; ++nn) {
    int node = nodeBase + nn;
    float sval = 0.f, hval = 0.f;
    if (node < N) {
      int s0 = rp_f[node], e0 = rp_f[node+1];
      float accf = 0.f;
      for (int base=s0; base<e0; base+=64) {
        int m = e0-base; if (m>64) m=64;
        int jv = (lane<m) ? col_f[base+lane] : 0;
        float a0=0.f,a1=0.f,a2=0.f,a3=0.f,a4=0.f,a5=0.f,a6=0.f,a7=0.f;
        int q=0;
        for (; q+7<m; q+=8) {
          int j0=__shfl(jv,q),  j1=__shfl(jv,q+1);
          int j2=__shfl(jv,q+2),j3=__shfl(jv,q+3);
          int j4=__shfl(jv,q+4),j5=__shfl(jv,q+5);
          int j6=__shfl(jv,q+6),j7=__shfl(jv,q+7);
          a0 += bf2f(hbl[(size_t)j0*DD]); a1 += bf2f(hbl[(size_t)j1*DD]);
          a2 += bf2f(hbl[(size_t)j2*DD]); a3 += bf2f(hbl[(size_t)j3*DD]);
          a4 += bf2f(hbl[(size_t)j4*DD]); a5 += bf2f(hbl[(size_t)j5*DD]);
          a6 += bf2f(hbl[(size_t)j6*DD]); a7 += bf2f(hbl[(size_t)j7*DD]);
        }
        for (; q<m; ++q) { int j=__shfl(jv,q); a0 += bf2f(hbl[(size_t)j*DD]); }
        accf += ((a0+a1)+(a2+a3)) + ((a4+a5)+(a6+a7));
      }
      int s1 = rp_b[node], e1 = rp_b[node+1];
      float accb = 0.f;
      for (int base=s1; base<e1; base+=64) {
        int m = e1-base; if (m>64) m=64;
        int jv = (lane<m) ? col_b[base+lane] : 0;
        float a0=0.f,a1=0.f,a2=0.f,a3=0.f,a4=0.f,a5=0.f,a6=0.f,a7=0.f;
        int q=0;
        for (; q+7<m; q+=8) {
          int j0=__shfl(jv,q),  j1=__shfl(jv,q+1);
          int j2=__shfl(jv,q+2),j3=__shfl(jv,q+3);
          int j4=__shfl(jv,q+4),j5=__shfl(jv,q+5);
          int j6=__shfl(jv,q+6),j7=__shfl(jv,q+7);
          a0 += bf2f(hbl[(size_t)j0*DD]); a1 += bf2f(hbl[(size_t)j1*DD]);
          a2 += bf2f(hbl[(size_t)j2*DD]); a3 += bf2f(hbl[(size_t)j3*DD]);
          a4 += bf2f(hbl[(size_t)j4*DD]); a5 += bf2f(hbl[(size_t)j5*DD]);
          a6 += bf2f(hbl[(size_t)j6*DD]); a7 += bf2f(hbl[(size_t)j7*DD]);
        }
        for (; q<m; ++q) { int j=__shfl(jv,q); a0 += bf2f(hbl[(size_t)j*DD]); }
        accb += ((a0+a1)+(a2+a3)) + ((a4+a5)+(a6+a7));
      }
      float df = fmaxf((float)(e0-s0), 1.f);
      float db = fmaxf((float)(e1-s1), 1.f);
      sval = 0.5f*(accf/df + accb/db);   // fold the 0.5 here
      hval = hin[(size_t)node*DD+lane];
    }
    srow[wid*AG_NPW+nn][lane] = sval;
    hrow[wid*AG_NPW+nn][lane] = hval;
  }
  // no barrier needed: this wave wrote and will read only its own 8 rows

  float bv = bias[lane];
  float tacc[AG_NPW];
  #pragma unroll
  for (int nn=0; nn<AG_NPW; ++nn) tacc[nn]=bv;

  for (int k=0; k<DD; k+=4) {
    float w0 = Wl[(k+0)*DD+lane], w1 = Wl[(k+1)*DD+lane];
    float w2 = Wl[(k+2)*DD+lane], w3 = Wl[(k+3)*DD+lane];
    float r0 = Wr[(k+0)*DD+lane], r1 = Wr[(k+1)*DD+lane];
    float r2 = Wr[(k+2)*DD+lane], r3 = Wr[(k+3)*DD+lane];
    #pragma unroll
    for (int nn=0; nn<AG_NPW; ++nn) {
      float4 sv = *(const float4*)&srow[wid*AG_NPW+nn][k];
      float4 hv = *(const float4*)&hrow[wid*AG_NPW+nn][k];
      tacc[nn] += sv.x*w0 + sv.y*w1 + sv.z*w2 + sv.w*w3
                + hv.x*r0 + hv.y*r1 + hv.z*r2 + hv.w*r3;
    }
  }

  // write t + per-graph accumulate (batch is sorted -> few flushes)
  int gcur = -1; float gacc = 0.f;
  for (int nn=0; nn<AG_NPW; ++nn) {
    int node = nodeBase+nn;
    if (node >= N) break;
    t[(size_t)node*DD+lane] = tacc[nn];
    int g = batch[node];
    if (g != gcur) {
      if (gcur >= 0) atomicAdd(&gsum[gcur*DD+lane], gacc);
      gcur = g; gacc = 0.f;
    }
    gacc += tacc[nn];
  }
  if (gcur >= 0) atomicAdd(&gsum[gcur*DD+lane], gacc);
}

// ----------------- GraphNorm pass 1 -----------------
__global__ void norm1_kernel(float* __restrict__ t, const float* __restrict__ gsum,
                             const int* __restrict__ cnt, const int* __restrict__ batch,
                             const float* __restrict__ gms, float* __restrict__ vsum, int N)
{
  int wid = (blockIdx.x*blockDim.x + threadIdx.x) >> 6;
  int lane = threadIdx.x & 63;
  int base = wid*NRM_NPW;
  if (base >= N) return;
  float msv = gms[lane];
  int gcur = -1; float mean = 0.f; float vacc = 0.f;
  int end = base+NRM_NPW; if (end>N) end=N;
  for (int node=base; node<end; ++node) {
    int g = batch[node];
    if (g != gcur) {
      if (gcur>=0) atomicAdd(&vsum[gcur*DD+lane], vacc);
      vacc = 0.f;
      float invc = 1.f / fmaxf((float)cnt[g], 1.f);
      mean = gsum[g*DD+lane]*invc;
      gcur = g;
    }
    float u = t[(size_t)node*DD+lane] - msv*mean;
    t[(size_t)node*DD+lane] = u;
    vacc += u*u;
  }
  if (gcur>=0) atomicAdd(&vsum[gcur*DD+lane], vacc);
}

// ----------------- GraphNorm pass 2 (+ bf16 shadow write) -----------------
__global__ void norm2_kernel(const float* __restrict__ t, const float* __restrict__ vsum,
                             const int* __restrict__ cnt, const int* __restrict__ batch,
                             const float* __restrict__ gw, const float* __restrict__ gb,
                             float* __restrict__ h, ushort_t* __restrict__ hb,
                             int resid, int N)
{
  int wid = (blockIdx.x*blockDim.x + threadIdx.x) >> 6;
  int lane = threadIdx.x & 63;
  int base = wid*NRM_NPW;
  if (base >= N) return;
  float wv = gw[lane], bv = gb[lane];
  int gcur=-1; float rs=0.f;
  int end = base+NRM_NPW; if (end>N) end=N;
  for (int node=base; node<end; ++node) {
    int g = batch[node];
    if (g!=gcur) {
      float invc = 1.f/fmaxf((float)cnt[g],1.f);
      rs = rsqrtf(vsum[g*DD+lane]*invc + EPSV);
      gcur=g;
    }
    float u = t[(size_t)node*DD+lane];
    float y = wv*u*rs + bv;
    y = (y>=0.f) ? y : SLOPE*y;
    float hv = resid ? (h[(size_t)node*DD+lane] + y) : y;
    h[(size_t)node*DD+lane] = hv;
    hb[(size_t)node*DD+lane] = f2bf(hv);
  }
}

// ----------------- global mean pool -----------------
__global__ void pool_kernel(const float* __restrict__ h, const int* __restrict__ batch,
                            float* __restrict__ pout, int N)
{
  int wid = (blockIdx.x*blockDim.x + threadIdx.x) >> 6;
  int lane = threadIdx.x & 63;
  int base = wid*NRM_NPW;
  if (base>=N) return;
  int gcur=-1; float acc=0.f;
  int end=base+NRM_NPW; if (end>N) end=N;
  for (int node=base; node<end; ++node) {
    int g = batch[node];
    if (g!=gcur) { if (gcur>=0) atomicAdd(&pout[gcur*DD+lane],acc); acc=0.f; gcur=g; }
    acc += h[(size_t)node*DD+lane];
  }
  if (gcur>=0) atomicAdd(&pout[gcur*DD+lane],acc);
}

__global__ void finalize_kernel(const float* __restrict__ pout, const int* __restrict__ cnt,
                                float* __restrict__ out)
{
  int i = blockIdx.x*blockDim.x + threadIdx.x;
  if (i < GG*DD) {
    float invc = 1.f/fmaxf((float)cnt[i>>6],1.f);
    out[i] = pout[i]*invc;
  }
}

extern "C" void kernel_launch(void* const* d_in, const int* in_sizes, int n_in,
                              void* d_out, int out_size, void* d_ws, size_t ws_size,
                              hipStream_t stream)
{
  const float* x    = (const float*)d_in[0];
  const int*  ei    = (const int*)d_in[1];
  const int*  batch = (const int*)d_in[2];
  const float* W_l  = (const float*)d_in[3];
  const float* W_r  = (const float*)d_in[4];
  const float* bias = (const float*)d_in[5];
  const float* gn_w = (const float*)d_in[6];
  const float* gn_b = (const float*)d_in[7];
  const float* gn_ms= (const float*)d_in[8];

  int N = in_sizes[2];
  int E = in_sizes[1]/2;
  int L = in_sizes[5]/DD;
  const int* src = ei;
  const int* dst = ei + E;

  // ---- workspace layout: zero-zone first (single memset) ----
  char* p = (char*)d_ws;
  int*   deg   = (int*)p;   p += (size_t)2*N*4;        // [deg_f | deg_b]
  int*   cnt   = (int*)p;   p += GG*4;
  float* gsum  = (float*)p; p += (size_t)L*GG*DD*4;    // per-layer
  float* vsum  = (float*)p; p += (size_t)L*GG*DD*4;    // per-layer
  float* pout  = (float*)p; p += GG*DD*4;
  size_t zeroBytes = (char*)p - (char*)d_ws;

  float* h     = (float*)p; p += (size_t)N*DD*4;
  float* t     = (float*)p; p += (size_t)N*DD*4;
  ushort_t* hb = (ushort_t*)p; p += (size_t)N*DD*2;    // bf16 shadow for gathers
  int* rp_f    = (int*)p; p += (size_t)(N+1)*4;
  int* rp_b    = (int*)p; p += (size_t)(N+1)*4;
  int* cur_f   = (int*)p; p += (size_t)N*4;
  int* cur_b   = (int*)p; p += (size_t)N*4;
  int* col_f   = (int*)p; p += (size_t)E*4;
  int* col_b   = (int*)p; p += (size_t)E*4;
  int* partial = (int*)p; p += 256*4;

  int* deg_f = deg;
  int* deg_b = deg + N;

  hipMemsetAsync(d_ws, 0, zeroBytes, stream);

  int npp = (N + NPART-1)/NPART;
  int eg = 2048;                       // multiple of NPART
  deg_kernel<<<eg, 256, 0, stream>>>(src, dst, deg_f, deg_b, E, npp);
  cnt_kernel<<<391, 256, 0, stream>>>(batch, cnt, N);
  tobf16_kernel<<<2048, 256, 0, stream>>>(x, hb, N*DD);

  int nb2 = (2*N + 1023)/1024;         // <= 256
  block_sum_kernel<<<nb2, 1024, 0, stream>>>(deg, partial, 2*N);
  scan_partial_kernel<<<1, 256, 0, stream>>>(partial, nb2);
  block_scan_kernel<<<nb2, 1024, 0, stream>>>(deg, partial, rp_f, rp_b, cur_f, cur_b, N, E);

  fill_kernel<<<eg, 256, 0, stream>>>(src, dst, cur_f, cur_b, col_f, col_b, E, npp);

  int agBlocks = (N + AG_NODES-1)/AG_NODES;
  int nrmWaves = (N + NRM_NPW-1)/NRM_NPW;
  int nrmBlocks = (nrmWaves+3)/4;

  for (int i=0; i<L; ++i) {
    const float* hin = (i==0) ? x : h;
    float* gsum_i = gsum + (size_t)i*GG*DD;
    float* vsum_i = vsum + (size_t)i*GG*DD;
    agg_gemm_kernel<<<agBlocks, 512, 0, stream>>>(hin, hb,
                                                  W_l+(size_t)i*DD*DD, W_r+(size_t)i*DD*DD,
                                                  bias+(size_t)i*DD,
                                                  rp_f, col_f, rp_b, col_b, batch, t, gsum_i, N);
    norm1_kernel<<<nrmBlocks, 256, 0, stream>>>(t, gsum_i, cnt, batch, gn_ms+(size_t)i*DD, vsum_i, N);
    norm2_kernel<<<nrmBlocks, 256, 0, stream>>>(t, vsum_i, cnt, batch, gn_w+(size_t)i*DD,
                                                gn_b+(size_t)i*DD, h, hb, (i>=2)?1:0, N);
  }
  pool_kernel<<<nrmBlocks, 256, 0, stream>>>(h, batch, pout, N);
  finalize_kernel<<<16, 256, 0, stream>>>(pout, cnt, (float*)d_out);
}

// Round 8
// 1150.767 us; speedup vs baseline: 1.3842x; 1.3543x over previous
//
#include <hip/hip_runtime.h>

#define DD 64
#define GG 64
#define EPSV 1e-5f
#define SLOPE 0.01f

#define AG_WAVES 8
#define AG_NPW 8
#define AG_NODES (AG_WAVES*AG_NPW) // 64 nodes per block (gemm kernel)
#define NRM_NPW 16
#define NPART 8                    // XCD count on MI355X

typedef unsigned short ushort_t;
typedef unsigned int uint_t;

__device__ __forceinline__ ushort_t f2bf(float f) {
  uint_t u = __float_as_uint(f);
  uint_t r = (u + 0x7fffu + ((u >> 16) & 1u)) >> 16;   // round-to-nearest-even
  return (ushort_t)r;
}
__device__ __forceinline__ float bflo(uint_t v) { return __uint_as_float(v << 16); }
__device__ __forceinline__ float bfhi(uint_t v) { return __uint_as_float(v & 0xffff0000u); }

// ----------------- CSR build (XCD-partitioned scatter) -----------------
__global__ void deg_kernel(const int* __restrict__ src, const int* __restrict__ dst,
                           int* __restrict__ deg_f, int* __restrict__ deg_b,
                           int E, int npp) {
  int part = blockIdx.x & (NPART-1);
  int lo = part*npp, hi = lo+npp;
  int tid = (blockIdx.x >> 3)*blockDim.x + threadIdx.x;
  int stride = (gridDim.x >> 3)*blockDim.x;
  for (int e=tid; e<E; e+=stride) {
    int d = dst[e], s = src[e];
    if (d >= lo && d < hi) atomicAdd(&deg_f[d], 1);
    if (s >= lo && s < hi) atomicAdd(&deg_b[s], 1);
  }
}

__global__ void fill_kernel(const int* __restrict__ src, const int* __restrict__ dst,
                            int* __restrict__ cur_f, int* __restrict__ cur_b,
                            int* __restrict__ col_f, int* __restrict__ col_b,
                            int E, int npp) {
  int part = blockIdx.x & (NPART-1);
  int lo = part*npp, hi = lo+npp;
  int tid = (blockIdx.x >> 3)*blockDim.x + threadIdx.x;
  int stride = (gridDim.x >> 3)*blockDim.x;
  for (int e=tid; e<E; e+=stride) {
    int s = src[e], d = dst[e];
    if (d >= lo && d < hi) { int p = atomicAdd(&cur_f[d], 1); col_f[p] = s; }
    if (s >= lo && s < hi) { int q = atomicAdd(&cur_b[s], 1); col_b[q] = d; }
  }
}

// ----------------- fused scan over concatenated [deg_f | deg_b] (2N) -----------------
__global__ void block_sum_kernel(const int* __restrict__ v, int* __restrict__ partial, int M) {
  __shared__ int sm[1024];
  int i = blockIdx.x*1024 + threadIdx.x;
  sm[threadIdx.x] = (i<M) ? v[i] : 0;
  __syncthreads();
  for (int s=512; s>0; s>>=1) {
    if (threadIdx.x < s) sm[threadIdx.x] += sm[threadIdx.x+s];
    __syncthreads();
  }
  if (threadIdx.x==0) partial[blockIdx.x] = sm[0];
}

__global__ void scan_partial_kernel(int* __restrict__ partial, int nb) {
  __shared__ int sm[256];
  int t = threadIdx.x;
  int v = (t<nb) ? partial[t] : 0;
  int orig = v;
  sm[t] = v; __syncthreads();
  for (int off=1; off<256; off<<=1) {
    int a = (t>=off) ? sm[t-off] : 0;
    __syncthreads();
    v += a; sm[t] = v;
    __syncthreads();
  }
  if (t<nb) partial[t] = v - orig;   // exclusive block offsets
}

__global__ void block_scan_kernel(const int* __restrict__ deg, const int* __restrict__ partial,
                                  int* __restrict__ rp_f, int* __restrict__ rp_b,
                                  int* __restrict__ cur_f, int* __restrict__ cur_b,
                                  int N, int E) {
  __shared__ int sm[1024];
  int i = blockIdx.x*1024 + threadIdx.x;
  int v = (i<2*N) ? deg[i] : 0;
  int orig = v;
  sm[threadIdx.x] = v; __syncthreads();
  for (int off=1; off<1024; off<<=1) {
    int a = (threadIdx.x>=off) ? sm[threadIdx.x-off] : 0;
    __syncthreads();
    v += a; sm[threadIdx.x] = v;
    __syncthreads();
  }
  int excl = v - orig + partial[blockIdx.x];
  if (i < N)        { rp_f[i] = excl;     cur_f[i] = excl; }
  else if (i < 2*N) { rp_b[i-N] = excl-E; cur_b[i-N] = excl-E; }  // sum(deg_f)==E
  if (blockIdx.x==0 && threadIdx.x==0) { rp_f[N] = E; rp_b[N] = E; }
}

__global__ void cnt_kernel(const int* __restrict__ batch, int* __restrict__ cnt, int N) {
  __shared__ int hist[GG];
  if (threadIdx.x < GG) hist[threadIdx.x] = 0;
  __syncthreads();
  int i = blockIdx.x*blockDim.x + threadIdx.x;
  int stride = gridDim.x*blockDim.x;
  for (int n=i; n<N; n+=stride) atomicAdd(&hist[batch[n]], 1);
  __syncthreads();
  if (threadIdx.x < GG) atomicAdd(&cnt[threadIdx.x], hist[threadIdx.x]);
}

// ----------------- fp32 -> bf16 shadow -----------------
__global__ void tobf16_kernel(const float* __restrict__ in, ushort_t* __restrict__ out, int M) {
  int i = blockIdx.x*blockDim.x + threadIdx.x;
  int stride = gridDim.x*blockDim.x;
  for (int k=i; k<M; k+=stride) out[k] = f2bf(in[k]);
}

// ----------------- gather: one wave per node, 2 neighbor rows per load instr ----------
// lane = 32*half + fp; fp indexes a feature PAIR (uint = 2 bf16). The two
// half-waves process interleaved neighbor subsets; shfl_xor(32) merges.
// No LDS, small VGPR -> max waves/CU -> max outstanding misses.
// Main unrolled body runs ONLY while all 8 shfl'd lane indices are valid
// (2*q+8 <= m); guarded tail handles the rest. (Round-7 NaN was an OOB here.)
__global__ __launch_bounds__(256) void gather_kernel(
    const ushort_t* __restrict__ hb,
    const int* __restrict__ rp_f, const int* __restrict__ col_f,
    const int* __restrict__ rp_b, const int* __restrict__ col_b,
    float* __restrict__ sbuf, int N)
{
  int w = (blockIdx.x*(blockDim.x>>6)) + (threadIdx.x>>6);   // node = global wave id
  if (w >= N) return;
  int lane = threadIdx.x & 63;
  int half = lane >> 5;
  int fp = lane & 31;
  const uint_t* hbp = (const uint_t*)hb;   // hbp[j*32 + fp] = features {2fp, 2fp+1} of row j

  float accf0=0.f, accf1=0.f, accb0=0.f, accb1=0.f;
  int degf, degb;

  // ---- forward ----
  {
    int s0 = rp_f[w], e0 = rp_f[w+1];
    degf = e0 - s0;
    for (int base=s0; base<e0; base+=64) {
      int m = e0-base; if (m>64) m=64;
      int jv = (lane<m) ? col_f[base+lane] : -1;
      int npair = (m+1)>>1;
      int q=0;
      float c00=0,c01=0,c10=0,c11=0,c20=0,c21=0,c30=0,c31=0;
      for (; 2*q+8 <= m; q+=4) {                 // all 8 lanes (2q..2q+7) valid
        int j0=__shfl(jv,2*q+half),   j1=__shfl(jv,2*q+2+half);
        int j2=__shfl(jv,2*q+4+half), j3=__shfl(jv,2*q+6+half);
        uint_t v0=hbp[(size_t)j0*32+fp], v1=hbp[(size_t)j1*32+fp];
        uint_t v2=hbp[(size_t)j2*32+fp], v3=hbp[(size_t)j3*32+fp];
        c00+=bflo(v0); c01+=bfhi(v0); c10+=bflo(v1); c11+=bfhi(v1);
        c20+=bflo(v2); c21+=bfhi(v2); c30+=bflo(v3); c31+=bfhi(v3);
      }
      for (; q<npair; ++q) {
        int j=__shfl(jv,2*q+half);
        if (j>=0) { uint_t v=hbp[(size_t)j*32+fp]; c00+=bflo(v); c01+=bfhi(v); }
      }
      accf0 += (c00+c10)+(c20+c30);
      accf1 += (c01+c11)+(c21+c31);
    }
  }
  // ---- backward ----
  {
    int s1 = rp_b[w], e1 = rp_b[w+1];
    degb = e1 - s1;
    for (int base=s1; base<e1; base+=64) {
      int m = e1-base; if (m>64) m=64;
      int jv = (lane<m) ? col_b[base+lane] : -1;
      int npair = (m+1)>>1;
      int q=0;
      float c00=0,c01=0,c10=0,c11=0,c20=0,c21=0,c30=0,c31=0;
      for (; 2*q+8 <= m; q+=4) {                 // all 8 lanes valid
        int j0=__shfl(jv,2*q+half),   j1=__shfl(jv,2*q+2+half);
        int j2=__shfl(jv,2*q+4+half), j3=__shfl(jv,2*q+6+half);
        uint_t v0=hbp[(size_t)j0*32+fp], v1=hbp[(size_t)j1*32+fp];
        uint_t v2=hbp[(size_t)j2*32+fp], v3=hbp[(size_t)j3*32+fp];
        c00+=bflo(v0); c01+=bfhi(v0); c10+=bflo(v1); c11+=bfhi(v1);
        c20+=bflo(v2); c21+=bfhi(v2); c30+=bflo(v3); c31+=bfhi(v3);
      }
      for (; q<npair; ++q) {
        int j=__shfl(jv,2*q+half);
        if (j>=0) { uint_t v=hbp[(size_t)j*32+fp]; c00+=bflo(v); c01+=bfhi(v); }
      }
      accb0 += (c00+c10)+(c20+c30);
      accb1 += (c01+c11)+(c21+c31);
    }
  }

  float df = fmaxf((float)degf, 1.f);
  float db = fmaxf((float)degb, 1.f);
  float s0v = 0.5f*(accf0/df + accb0/db);   // partial (this half's neighbor subset)
  float s1v = 0.5f*(accf1/df + accb1/db);
  s0v += __shfl_xor(s0v, 32);               // merge halves
  s1v += __shfl_xor(s1v, 32);
  if (half==0) {
    float2* o = (float2*)&sbuf[(size_t)w*DD + 2*fp];
    *o = make_float2(s0v, s1v);
  }
}

// ----------------- dual GEMM + graph-sum (streaming, no gather) -----------------
// No __syncthreads: each wave owns srow/hrow rows [wid*8 .. wid*8+7].
__global__ __launch_bounds__(512) void gemm_kernel(
    const float* __restrict__ hin, const float* __restrict__ sbuf,
    const float* __restrict__ Wl, const float* __restrict__ Wr, const float* __restrict__ bias,
    const int* __restrict__ batch,
    float* __restrict__ t, float* __restrict__ gsum, int N)
{
  __shared__ float srow[AG_NODES][DD];
  __shared__ float hrow[AG_NODES][DD];

  int wid = threadIdx.x >> 6;
  int lane = threadIdx.x & 63;
  int nodeBase = blockIdx.x*AG_NODES + wid*AG_NPW;

  for (int nn=0; nn<AG_NPW; ++nn) {
    int node = nodeBase + nn;
    float sval = 0.f, hval = 0.f;
    if (node < N) {
      sval = sbuf[(size_t)node*DD+lane];
      hval = hin[(size_t)node*DD+lane];
    }
    srow[wid*AG_NPW+nn][lane] = sval;
    hrow[wid*AG_NPW+nn][lane] = hval;
  }

  float bv = bias[lane];
  float tacc[AG_NPW];
  #pragma unroll
  for (int nn=0; nn<AG_NPW; ++nn) tacc[nn]=bv;

  for (int k=0; k<DD; k+=4) {
    float w0 = Wl[(k+0)*DD+lane], w1 = Wl[(k+1)*DD+lane];
    float w2 = Wl[(k+2)*DD+lane], w3 = Wl[(k+3)*DD+lane];
    float r0 = Wr[(k+0)*DD+lane], r1 = Wr[(k+1)*DD+lane];
    float r2 = Wr[(k+2)*DD+lane], r3 = Wr[(k+3)*DD+lane];
    #pragma unroll
    for (int nn=0; nn<AG_NPW; ++nn) {
      float4 sv = *(const float4*)&srow[wid*AG_NPW+nn][k];
      float4 hv = *(const float4*)&hrow[wid*AG_NPW+nn][k];
      tacc[nn] += sv.x*w0 + sv.y*w1 + sv.z*w2 + sv.w*w3
                + hv.x*r0 + hv.y*r1 + hv.z*r2 + hv.w*r3;
    }
  }

  int gcur = -1; float gacc = 0.f;
  for (int nn=0; nn<AG_NPW; ++nn) {
    int node = nodeBase+nn;
    if (node >= N) break;
    t[(size_t)node*DD+lane] = tacc[nn];
    int g = batch[node];
    if (g != gcur) {
      if (gcur >= 0) atomicAdd(&gsum[gcur*DD+lane], gacc);
      gcur = g; gacc = 0.f;
    }
    gacc += tacc[nn];
  }
  if (gcur >= 0) atomicAdd(&gsum[gcur*DD+lane], gacc);
}

// ----------------- GraphNorm pass 1 -----------------
__global__ void norm1_kernel(float* __restrict__ t, const float* __restrict__ gsum,
                             const int* __restrict__ cnt, const int* __restrict__ batch,
                             const float* __restrict__ gms, float* __restrict__ vsum, int N)
{
  int wid = (blockIdx.x*blockDim.x + threadIdx.x) >> 6;
  int lane = threadIdx.x & 63;
  int base = wid*NRM_NPW;
  if (base >= N) return;
  float msv = gms[lane];
  int gcur = -1; float mean = 0.f; float vacc = 0.f;
  int end = base+NRM_NPW; if (end>N) end=N;
  for (int node=base; node<end; ++node) {
    int g = batch[node];
    if (g != gcur) {
      if (gcur>=0) atomicAdd(&vsum[gcur*DD+lane], vacc);
      vacc = 0.f;
      float invc = 1.f / fmaxf((float)cnt[g], 1.f);
      mean = gsum[g*DD+lane]*invc;
      gcur = g;
    }
    float u = t[(size_t)node*DD+lane] - msv*mean;
    t[(size_t)node*DD+lane] = u;
    vacc += u*u;
  }
  if (gcur>=0) atomicAdd(&vsum[gcur*DD+lane], vacc);
}

// ----------------- GraphNorm pass 2 (+ bf16 shadow write) -----------------
__global__ void norm2_kernel(const float* __restrict__ t, const float* __restrict__ vsum,
                             const int* __restrict__ cnt, const int* __restrict__ batch,
                             const float* __restrict__ gw, const float* __restrict__ gb,
                             float* __restrict__ h, ushort_t* __restrict__ hb,
                             int resid, int N)
{
  int wid = (blockIdx.x*blockDim.x + threadIdx.x) >> 6;
  int lane = threadIdx.x & 63;
  int base = wid*NRM_NPW;
  if (base >= N) return;
  float wv = gw[lane], bv = gb[lane];
  int gcur=-1; float rs=0.f;
  int end = base+NRM_NPW; if (end>N) end=N;
  for (int node=base; node<end; ++node) {
    int g = batch[node];
    if (g!=gcur) {
      float invc = 1.f/fmaxf((float)cnt[g],1.f);
      rs = rsqrtf(vsum[g*DD+lane]*invc + EPSV);
      gcur=g;
    }
    float u = t[(size_t)node*DD+lane];
    float y = wv*u*rs + bv;
    y = (y>=0.f) ? y : SLOPE*y;
    float hv = resid ? (h[(size_t)node*DD+lane] + y) : y;
    h[(size_t)node*DD+lane] = hv;
    hb[(size_t)node*DD+lane] = f2bf(hv);
  }
}

// ----------------- global mean pool -----------------
__global__ void pool_kernel(const float* __restrict__ h, const int* __restrict__ batch,
                            float* __restrict__ pout, int N)
{
  int wid = (blockIdx.x*blockDim.x + threadIdx.x) >> 6;
  int lane = threadIdx.x & 63;
  int base = wid*NRM_NPW;
  if (base>=N) return;
  int gcur=-1; float acc=0.f;
  int end=base+NRM_NPW; if (end>N) end=N;
  for (int node=base; node<end; ++node) {
    int g = batch[node];
    if (g!=gcur) { if (gcur>=0) atomicAdd(&pout[gcur*DD+lane],acc); acc=0.f; gcur=g; }
    acc += h[(size_t)node*DD+lane];
  }
  if (gcur>=0) atomicAdd(&pout[gcur*DD+lane],acc);
}

__global__ void finalize_kernel(const float* __restrict__ pout, const int* __restrict__ cnt,
                                float* __restrict__ out)
{
  int i = blockIdx.x*blockDim.x + threadIdx.x;
  if (i < GG*DD) {
    float invc = 1.f/fmaxf((float)cnt[i>>6],1.f);
    out[i] = pout[i]*invc;
  }
}

extern "C" void kernel_launch(void* const* d_in, const int* in_sizes, int n_in,
                              void* d_out, int out_size, void* d_ws, size_t ws_size,
                              hipStream_t stream)
{
  const float* x    = (const float*)d_in[0];
  const int*  ei    = (const int*)d_in[1];
  const int*  batch = (const int*)d_in[2];
  const float* W_l  = (const float*)d_in[3];
  const float* W_r  = (const float*)d_in[4];
  const float* bias = (const float*)d_in[5];
  const float* gn_w = (const float*)d_in[6];
  const float* gn_b = (const float*)d_in[7];
  const float* gn_ms= (const float*)d_in[8];

  int N = in_sizes[2];
  int E = in_sizes[1]/2;
  int L = in_sizes[5]/DD;
  const int* src = ei;
  const int* dst = ei + E;

  // ---- workspace layout: zero-zone first (single memset) ----
  char* p = (char*)d_ws;
  int*   deg   = (int*)p;   p += (size_t)2*N*4;        // [deg_f | deg_b]
  int*   cnt   = (int*)p;   p += GG*4;
  float* gsum  = (float*)p; p += (size_t)L*GG*DD*4;    // per-layer
  float* vsum  = (float*)p; p += (size_t)L*GG*DD*4;    // per-layer
  float* pout  = (float*)p; p += GG*DD*4;
  size_t zeroBytes = (char*)p - (char*)d_ws;

  float* h     = (float*)p; p += (size_t)N*DD*4;
  float* t     = (float*)p; p += (size_t)N*DD*4;
  float* sbuf  = (float*)p; p += (size_t)N*DD*4;       // aggregated means (fp32)
  ushort_t* hb = (ushort_t*)p; p += (size_t)N*DD*2;    // bf16 shadow for gathers
  int* rp_f    = (int*)p; p += (size_t)(N+1)*4;
  int* rp_b    = (int*)p; p += (size_t)(N+1)*4;
  int* cur_f   = (int*)p; p += (size_t)N*4;
  int* cur_b   = (int*)p; p += (size_t)N*4;
  int* col_f   = (int*)p; p += (size_t)E*4;
  int* col_b   = (int*)p; p += (size_t)E*4;
  int* partial = (int*)p; p += 256*4;

  int* deg_f = deg;
  int* deg_b = deg + N;

  hipMemsetAsync(d_ws, 0, zeroBytes, stream);

  int npp = (N + NPART-1)/NPART;
  int eg = 2048;                       // multiple of NPART
  deg_kernel<<<eg, 256, 0, stream>>>(src, dst, deg_f, deg_b, E, npp);
  cnt_kernel<<<391, 256, 0, stream>>>(batch, cnt, N);
  tobf16_kernel<<<2048, 256, 0, stream>>>(x, hb, N*DD);

  int nb2 = (2*N + 1023)/1024;         // <= 256
  block_sum_kernel<<<nb2, 1024, 0, stream>>>(deg, partial, 2*N);
  scan_partial_kernel<<<1, 256, 0, stream>>>(partial, nb2);
  block_scan_kernel<<<nb2, 1024, 0, stream>>>(deg, partial, rp_f, rp_b, cur_f, cur_b, N, E);

  fill_kernel<<<eg, 256, 0, stream>>>(src, dst, cur_f, cur_b, col_f, col_b, E, npp);

  int gthBlocks = (N + 3)/4;           // 4 waves (nodes) per 256-thread block
  int agBlocks = (N + AG_NODES-1)/AG_NODES;
  int nrmWaves = (N + NRM_NPW-1)/NRM_NPW;
  int nrmBlocks = (nrmWaves+3)/4;

  for (int i=0; i<L; ++i) {
    const float* hin = (i==0) ? x : h;
    float* gsum_i = gsum + (size_t)i*GG*DD;
    float* vsum_i = vsum + (size_t)i*GG*DD;
    gather_kernel<<<gthBlocks, 256, 0, stream>>>(hb, rp_f, col_f, rp_b, col_b, sbuf, N);
    gemm_kernel<<<agBlocks, 512, 0, stream>>>(hin, sbuf,
                                              W_l+(size_t)i*DD*DD, W_r+(size_t)i*DD*DD,
                                              bias+(size_t)i*DD, batch, t, gsum_i, N);
    norm1_kernel<<<nrmBlocks, 256, 0, stream>>>(t, gsum_i, cnt, batch, gn_ms+(size_t)i*DD, vsum_i, N);
    norm2_kernel<<<nrmBlocks, 256, 0, stream>>>(t, vsum_i, cnt, batch, gn_w+(size_t)i*DD,
                                                gn_b+(size_t)i*DD, h, hb, (i>=2)?1:0, N);
  }
  pool_kernel<<<nrmBlocks, 256, 0, stream>>>(h, batch, pout, N);
  finalize_kernel<<<16, 256, 0, stream>>>(pout, cnt, (float*)d_out);
}

// Round 9
// 1106.180 us; speedup vs baseline: 1.4400x; 1.0403x over previous
//
#include <hip/hip_runtime.h>

#define DD 64
#define GG 64
#define EPSV 1e-5f
#define SLOPE 0.01f

#define AG_WAVES 8
#define AG_NPW 8
#define AG_NODES (AG_WAVES*AG_NPW) // 64 nodes per block (gemm kernel)
#define NRM_NPW 16
#define NPART 8                    // XCD count on MI355X

typedef unsigned short ushort_t;
typedef unsigned int uint_t;

__device__ __forceinline__ ushort_t f2bf(float f) {
  uint_t u = __float_as_uint(f);
  uint_t r = (u + 0x7fffu + ((u >> 16) & 1u)) >> 16;   // round-to-nearest-even
  return (ushort_t)r;
}
__device__ __forceinline__ float bflo(uint_t v) { return __uint_as_float(v << 16); }
__device__ __forceinline__ float bfhi(uint_t v) { return __uint_as_float(v & 0xffff0000u); }

// ----------------- CSR build (XCD-partitioned scatter, NT edge reads) -----------------
// nt loads keep the 12.8MB edge stream out of L2 so the partition's col/cur
// lines stay resident until full -> writebacks ~= logical bytes.
__global__ void deg_kernel(const int* __restrict__ src, const int* __restrict__ dst,
                           int* __restrict__ deg_f, int* __restrict__ deg_b,
                           int E, int npp) {
  int part = blockIdx.x & (NPART-1);
  int lo = part*npp, hi = lo+npp;
  int tid = (blockIdx.x >> 3)*blockDim.x + threadIdx.x;
  int stride = (gridDim.x >> 3)*blockDim.x;
  for (int e=tid; e<E; e+=stride) {
    int d = __builtin_nontemporal_load(&dst[e]);
    int s = __builtin_nontemporal_load(&src[e]);
    if (d >= lo && d < hi) atomicAdd(&deg_f[d], 1);
    if (s >= lo && s < hi) atomicAdd(&deg_b[s], 1);
  }
}

__global__ void fill_kernel(const int* __restrict__ src, const int* __restrict__ dst,
                            int* __restrict__ cur_f, int* __restrict__ cur_b,
                            int* __restrict__ col_f, int* __restrict__ col_b,
                            int E, int npp) {
  int part = blockIdx.x & (NPART-1);
  int lo = part*npp, hi = lo+npp;
  int tid = (blockIdx.x >> 3)*blockDim.x + threadIdx.x;
  int stride = (gridDim.x >> 3)*blockDim.x;
  for (int e=tid; e<E; e+=stride) {
    int s = __builtin_nontemporal_load(&src[e]);
    int d = __builtin_nontemporal_load(&dst[e]);
    if (d >= lo && d < hi) { int p = atomicAdd(&cur_f[d], 1); col_f[p] = s; }
    if (s >= lo && s < hi) { int q = atomicAdd(&cur_b[s], 1); col_b[q] = d; }
  }
}

// ----------------- fused scan over concatenated [deg_f | deg_b] (2N) -----------------
__global__ void block_sum_kernel(const int* __restrict__ v, int* __restrict__ partial, int M) {
  __shared__ int sm[1024];
  int i = blockIdx.x*1024 + threadIdx.x;
  sm[threadIdx.x] = (i<M) ? v[i] : 0;
  __syncthreads();
  for (int s=512; s>0; s>>=1) {
    if (threadIdx.x < s) sm[threadIdx.x] += sm[threadIdx.x+s];
    __syncthreads();
  }
  if (threadIdx.x==0) partial[blockIdx.x] = sm[0];
}

__global__ void scan_partial_kernel(int* __restrict__ partial, int nb) {
  __shared__ int sm[256];
  int t = threadIdx.x;
  int v = (t<nb) ? partial[t] : 0;
  int orig = v;
  sm[t] = v; __syncthreads();
  for (int off=1; off<256; off<<=1) {
    int a = (t>=off) ? sm[t-off] : 0;
    __syncthreads();
    v += a; sm[t] = v;
    __syncthreads();
  }
  if (t<nb) partial[t] = v - orig;   // exclusive block offsets
}

__global__ void block_scan_kernel(const int* __restrict__ deg, const int* __restrict__ partial,
                                  int* __restrict__ rp_f, int* __restrict__ rp_b,
                                  int* __restrict__ cur_f, int* __restrict__ cur_b,
                                  int N, int E) {
  __shared__ int sm[1024];
  int i = blockIdx.x*1024 + threadIdx.x;
  int v = (i<2*N) ? deg[i] : 0;
  int orig = v;
  sm[threadIdx.x] = v; __syncthreads();
  for (int off=1; off<1024; off<<=1) {
    int a = (threadIdx.x>=off) ? sm[threadIdx.x-off] : 0;
    __syncthreads();
    v += a; sm[threadIdx.x] = v;
    __syncthreads();
  }
  int excl = v - orig + partial[blockIdx.x];
  if (i < N)        { rp_f[i] = excl;     cur_f[i] = excl; }
  else if (i < 2*N) { rp_b[i-N] = excl-E; cur_b[i-N] = excl-E; }  // sum(deg_f)==E
  if (blockIdx.x==0 && threadIdx.x==0) { rp_f[N] = E; rp_b[N] = E; }
}

__global__ void cnt_kernel(const int* __restrict__ batch, int* __restrict__ cnt, int N) {
  __shared__ int hist[GG];
  if (threadIdx.x < GG) hist[threadIdx.x] = 0;
  __syncthreads();
  int i = blockIdx.x*blockDim.x + threadIdx.x;
  int stride = gridDim.x*blockDim.x;
  for (int n=i; n<N; n+=stride) atomicAdd(&hist[batch[n]], 1);
  __syncthreads();
  if (threadIdx.x < GG) atomicAdd(&cnt[threadIdx.x], hist[threadIdx.x]);
}

// ----------------- fp32 -> bf16 shadow -----------------
__global__ void tobf16_kernel(const float* __restrict__ in, ushort_t* __restrict__ out, int M) {
  int i = blockIdx.x*blockDim.x + threadIdx.x;
  int stride = gridDim.x*blockDim.x;
  for (int k=i; k<M; k+=stride) out[k] = f2bf(in[k]);
}

// ----------------- gather: one wave per node, uint2 loads (4 rows / wave-instr) -----
// lane = 16*qt + g; g indexes a feature QUAD (uint2 = 4 bf16). The 4 quarter-
// waves process neighbor subsets idx===qt (mod 4); shfl_xor(16,32) merges.
// Main unrolled body requires lanes 4q..4q+15 valid (4q+16 <= m); exact
// per-quarter tail handles the rest (no OOB possible).
__global__ __launch_bounds__(256) void gather_kernel(
    const ushort_t* __restrict__ hb,
    const int* __restrict__ rp_f, const int* __restrict__ col_f,
    const int* __restrict__ rp_b, const int* __restrict__ col_b,
    float* __restrict__ sbuf, int N)
{
  int w = (blockIdx.x*(blockDim.x>>6)) + (threadIdx.x>>6);   // node = global wave id
  if (w >= N) return;
  int lane = threadIdx.x & 63;
  int qt = lane >> 4;        // quarter 0..3
  int g  = lane & 15;        // feature quad: features 4g..4g+3
  const uint2* hbp = (const uint2*)hb;   // hbp[j*16+g] = bf16 features 4g..4g+3 of row j

  float f0=0.f,f1=0.f,f2=0.f,f3=0.f, b0=0.f,b1=0.f,b2=0.f,b3=0.f;
  int degf, degb;

  // ---- forward ----
  {
    int s0 = rp_f[w], e0 = rp_f[w+1];
    degf = e0 - s0;
    for (int base=s0; base<e0; base+=64) {
      int m = e0-base; if (m>64) m=64;
      int jv = (lane<m) ? col_f[base+lane] : 0;
      int q=0;
      for (; 4*q+16 <= m; q+=4) {
        int j0=__shfl(jv,4*q+qt),    j1=__shfl(jv,4*q+4+qt);
        int j2=__shfl(jv,4*q+8+qt),  j3=__shfl(jv,4*q+12+qt);
        uint2 v0=hbp[(size_t)j0*16+g], v1=hbp[(size_t)j1*16+g];
        uint2 v2=hbp[(size_t)j2*16+g], v3=hbp[(size_t)j3*16+g];
        f0 += (bflo(v0.x)+bflo(v1.x))+(bflo(v2.x)+bflo(v3.x));
        f1 += (bfhi(v0.x)+bfhi(v1.x))+(bfhi(v2.x)+bfhi(v3.x));
        f2 += (bflo(v0.y)+bflo(v1.y))+(bflo(v2.y)+bflo(v3.y));
        f3 += (bfhi(v0.y)+bfhi(v1.y))+(bfhi(v2.y)+bfhi(v3.y));
      }
      for (; 4*q+qt < m; ++q) {
        int j=__shfl(jv,4*q+qt);
        uint2 v=hbp[(size_t)j*16+g];
        f0+=bflo(v.x); f1+=bfhi(v.x); f2+=bflo(v.y); f3+=bfhi(v.y);
      }
    }
  }
  // ---- backward ----
  {
    int s1 = rp_b[w], e1 = rp_b[w+1];
    degb = e1 - s1;
    for (int base=s1; base<e1; base+=64) {
      int m = e1-base; if (m>64) m=64;
      int jv = (lane<m) ? col_b[base+lane] : 0;
      int q=0;
      for (; 4*q+16 <= m; q+=4) {
        int j0=__shfl(jv,4*q+qt),    j1=__shfl(jv,4*q+4+qt);
        int j2=__shfl(jv,4*q+8+qt),  j3=__shfl(jv,4*q+12+qt);
        uint2 v0=hbp[(size_t)j0*16+g], v1=hbp[(size_t)j1*16+g];
        uint2 v2=hbp[(size_t)j2*16+g], v3=hbp[(size_t)j3*16+g];
        b0 += (bflo(v0.x)+bflo(v1.x))+(bflo(v2.x)+bflo(v3.x));
        b1 += (bfhi(v0.x)+bfhi(v1.x))+(bfhi(v2.x)+bfhi(v3.x));
        b2 += (bflo(v0.y)+bflo(v1.y))+(bflo(v2.y)+bflo(v3.y));
        b3 += (bfhi(v0.y)+bfhi(v1.y))+(bfhi(v2.y)+bfhi(v3.y));
      }
      for (; 4*q+qt < m; ++q) {
        int j=__shfl(jv,4*q+qt);
        uint2 v=hbp[(size_t)j*16+g];
        b0+=bflo(v.x); b1+=bfhi(v.x); b2+=bflo(v.y); b3+=bfhi(v.y);
      }
    }
  }

  float df = fmaxf((float)degf, 1.f);
  float db = fmaxf((float)degb, 1.f);
  float s0v = 0.5f*(f0/df + b0/db);
  float s1v = 0.5f*(f1/df + b1/db);
  float s2v = 0.5f*(f2/df + b2/db);
  float s3v = 0.5f*(f3/df + b3/db);
  s0v += __shfl_xor(s0v,16); s0v += __shfl_xor(s0v,32);
  s1v += __shfl_xor(s1v,16); s1v += __shfl_xor(s1v,32);
  s2v += __shfl_xor(s2v,16); s2v += __shfl_xor(s2v,32);
  s3v += __shfl_xor(s3v,16); s3v += __shfl_xor(s3v,32);
  if (qt==0) {
    float4* o = (float4*)&sbuf[(size_t)w*DD + 4*g];
    *o = make_float4(s0v, s1v, s2v, s3v);
  }
}

// ----------------- dual GEMM + graph-sum (streaming) -----------------
// No __syncthreads: each wave owns srow/hrow rows [wid*8 .. wid*8+7].
__global__ __launch_bounds__(512) void gemm_kernel(
    const float* __restrict__ hin, const float* __restrict__ sbuf,
    const float* __restrict__ Wl, const float* __restrict__ Wr, const float* __restrict__ bias,
    const int* __restrict__ batch,
    float* __restrict__ t, float* __restrict__ gsum, int N)
{
  __shared__ float srow[AG_NODES][DD];
  __shared__ float hrow[AG_NODES][DD];

  int wid = threadIdx.x >> 6;
  int lane = threadIdx.x & 63;
  int nodeBase = blockIdx.x*AG_NODES + wid*AG_NPW;

  for (int nn=0; nn<AG_NPW; ++nn) {
    int node = nodeBase + nn;
    float sval = 0.f, hval = 0.f;
    if (node < N) {
      sval = sbuf[(size_t)node*DD+lane];
      hval = hin[(size_t)node*DD+lane];
    }
    srow[wid*AG_NPW+nn][lane] = sval;
    hrow[wid*AG_NPW+nn][lane] = hval;
  }

  float bv = bias[lane];
  float tacc[AG_NPW];
  #pragma unroll
  for (int nn=0; nn<AG_NPW; ++nn) tacc[nn]=bv;

  for (int k=0; k<DD; k+=4) {
    float w0 = Wl[(k+0)*DD+lane], w1 = Wl[(k+1)*DD+lane];
    float w2 = Wl[(k+2)*DD+lane], w3 = Wl[(k+3)*DD+lane];
    float r0 = Wr[(k+0)*DD+lane], r1 = Wr[(k+1)*DD+lane];
    float r2 = Wr[(k+2)*DD+lane], r3 = Wr[(k+3)*DD+lane];
    #pragma unroll
    for (int nn=0; nn<AG_NPW; ++nn) {
      float4 sv = *(const float4*)&srow[wid*AG_NPW+nn][k];
      float4 hv = *(const float4*)&hrow[wid*AG_NPW+nn][k];
      tacc[nn] += sv.x*w0 + sv.y*w1 + sv.z*w2 + sv.w*w3
                + hv.x*r0 + hv.y*r1 + hv.z*r2 + hv.w*r3;
    }
  }

  int gcur = -1; float gacc = 0.f;
  for (int nn=0; nn<AG_NPW; ++nn) {
    int node = nodeBase+nn;
    if (node >= N) break;
    t[(size_t)node*DD+lane] = tacc[nn];
    int g = batch[node];
    if (g != gcur) {
      if (gcur >= 0) atomicAdd(&gsum[gcur*DD+lane], gacc);
      gcur = g; gacc = 0.f;
    }
    gacc += tacc[nn];
  }
  if (gcur >= 0) atomicAdd(&gsum[gcur*DD+lane], gacc);
}

// ----------------- GraphNorm pass 1 (read-only over t: var accumulation) -----------------
__global__ void norm1_kernel(const float* __restrict__ t, const float* __restrict__ gsum,
                             const int* __restrict__ cnt, const int* __restrict__ batch,
                             const float* __restrict__ gms, float* __restrict__ vsum, int N)
{
  int wid = (blockIdx.x*blockDim.x + threadIdx.x) >> 6;
  int lane = threadIdx.x & 63;
  int base = wid*NRM_NPW;
  if (base >= N) return;
  float msv = gms[lane];
  int gcur = -1; float mean = 0.f; float vacc = 0.f;
  int end = base+NRM_NPW; if (end>N) end=N;
  for (int node=base; node<end; ++node) {
    int g = batch[node];
    if (g != gcur) {
      if (gcur>=0) atomicAdd(&vsum[gcur*DD+lane], vacc);
      vacc = 0.f;
      float invc = 1.f / fmaxf((float)cnt[g], 1.f);
      mean = gsum[g*DD+lane]*invc;
      gcur = g;
    }
    float u = t[(size_t)node*DD+lane] - msv*mean;
    vacc += u*u;
  }
  if (gcur>=0) atomicAdd(&vsum[gcur*DD+lane], vacc);
}

// ----------------- GraphNorm pass 2 (recompute u; last layer fuses pool) -----------------
__global__ void norm2_kernel(const float* __restrict__ t, const float* __restrict__ vsum,
                             const float* __restrict__ gsum,
                             const int* __restrict__ cnt, const int* __restrict__ batch,
                             const float* __restrict__ gw, const float* __restrict__ gb,
                             const float* __restrict__ gms,
                             float* __restrict__ h, ushort_t* __restrict__ hb,
                             float* __restrict__ pout,
                             int resid, int last, int N)
{
  int wid = (blockIdx.x*blockDim.x + threadIdx.x) >> 6;
  int lane = threadIdx.x & 63;
  int base = wid*NRM_NPW;
  if (base >= N) return;
  float wv = gw[lane], bv = gb[lane], msv = gms[lane];
  int gcur=-1; float rs=0.f, mean=0.f, pacc=0.f;
  int end = base+NRM_NPW; if (end>N) end=N;
  for (int node=base; node<end; ++node) {
    int g = batch[node];
    if (g!=gcur) {
      if (last && gcur>=0) atomicAdd(&pout[gcur*DD+lane], pacc);
      pacc = 0.f;
      float invc = 1.f/fmaxf((float)cnt[g],1.f);
      mean = gsum[g*DD+lane]*invc;
      rs = rsqrtf(vsum[g*DD+lane]*invc + EPSV);
      gcur=g;
    }
    float u = t[(size_t)node*DD+lane] - msv*mean;
    float y = wv*u*rs + bv;
    y = (y>=0.f) ? y : SLOPE*y;
    float hv = resid ? (h[(size_t)node*DD+lane] + y) : y;
    if (last) {
      pacc += hv;                       // final h never re-read: pool only
    } else {
      h[(size_t)node*DD+lane] = hv;
      hb[(size_t)node*DD+lane] = f2bf(hv);
    }
  }
  if (last && gcur>=0) atomicAdd(&pout[gcur*DD+lane], pacc);
}

__global__ void finalize_kernel(const float* __restrict__ pout, const int* __restrict__ cnt,
                                float* __restrict__ out)
{
  int i = blockIdx.x*blockDim.x + threadIdx.x;
  if (i < GG*DD) {
    float invc = 1.f/fmaxf((float)cnt[i>>6],1.f);
    out[i] = pout[i]*invc;
  }
}

extern "C" void kernel_launch(void* const* d_in, const int* in_sizes, int n_in,
                              void* d_out, int out_size, void* d_ws, size_t ws_size,
                              hipStream_t stream)
{
  const float* x    = (const float*)d_in[0];
  const int*  ei    = (const int*)d_in[1];
  const int*  batch = (const int*)d_in[2];
  const float* W_l  = (const float*)d_in[3];
  const float* W_r  = (const float*)d_in[4];
  const float* bias = (const float*)d_in[5];
  const float* gn_w = (const float*)d_in[6];
  const float* gn_b = (const float*)d_in[7];
  const float* gn_ms= (const float*)d_in[8];

  int N = in_sizes[2];
  int E = in_sizes[1]/2;
  int L = in_sizes[5]/DD;
  const int* src = ei;
  const int* dst = ei + E;

  // ---- workspace layout: zero-zone first (single memset) ----
  char* p = (char*)d_ws;
  int*   deg   = (int*)p;   p += (size_t)2*N*4;        // [deg_f | deg_b]
  int*   cnt   = (int*)p;   p += GG*4;
  float* gsum  = (float*)p; p += (size_t)L*GG*DD*4;    // per-layer
  float* vsum  = (float*)p; p += (size_t)L*GG*DD*4;    // per-layer
  float* pout  = (float*)p; p += GG*DD*4;
  size_t zeroBytes = (char*)p - (char*)d_ws;

  float* h     = (float*)p; p += (size_t)N*DD*4;
  float* t     = (float*)p; p += (size_t)N*DD*4;
  float* sbuf  = (float*)p; p += (size_t)N*DD*4;       // aggregated means (fp32)
  ushort_t* hb = (ushort_t*)p; p += (size_t)N*DD*2;    // bf16 shadow for gathers
  int* rp_f    = (int*)p; p += (size_t)(N+1)*4;
  int* rp_b    = (int*)p; p += (size_t)(N+1)*4;
  int* cur_f   = (int*)p; p += (size_t)N*4;
  int* cur_b   = (int*)p; p += (size_t)N*4;
  int* col_f   = (int*)p; p += (size_t)E*4;
  int* col_b   = (int*)p; p += (size_t)E*4;
  int* partial = (int*)p; p += 256*4;

  int* deg_f = deg;
  int* deg_b = deg + N;

  hipMemsetAsync(d_ws, 0, zeroBytes, stream);

  int npp = (N + NPART-1)/NPART;
  int eg = 2048;                       // multiple of NPART
  deg_kernel<<<eg, 256, 0, stream>>>(src, dst, deg_f, deg_b, E, npp);
  cnt_kernel<<<391, 256, 0, stream>>>(batch, cnt, N);
  tobf16_kernel<<<2048, 256, 0, stream>>>(x, hb, N*DD);

  int nb2 = (2*N + 1023)/1024;         // <= 256
  block_sum_kernel<<<nb2, 1024, 0, stream>>>(deg, partial, 2*N);
  scan_partial_kernel<<<1, 256, 0, stream>>>(partial, nb2);
  block_scan_kernel<<<nb2, 1024, 0, stream>>>(deg, partial, rp_f, rp_b, cur_f, cur_b, N, E);

  fill_kernel<<<eg, 256, 0, stream>>>(src, dst, cur_f, cur_b, col_f, col_b, E, npp);

  int gthBlocks = (N + 3)/4;           // 4 waves (nodes) per 256-thread block
  int agBlocks = (N + AG_NODES-1)/AG_NODES;
  int nrmWaves = (N + NRM_NPW-1)/NRM_NPW;
  int nrmBlocks = (nrmWaves+3)/4;

  for (int i=0; i<L; ++i) {
    const float* hin = (i==0) ? x : h;
    float* gsum_i = gsum + (size_t)i*GG*DD;
    float* vsum_i = vsum + (size_t)i*GG*DD;
    int last = (i==L-1) ? 1 : 0;
    gather_kernel<<<gthBlocks, 256, 0, stream>>>(hb, rp_f, col_f, rp_b, col_b, sbuf, N);
    gemm_kernel<<<agBlocks, 512, 0, stream>>>(hin, sbuf,
                                              W_l+(size_t)i*DD*DD, W_r+(size_t)i*DD*DD,
                                              bias+(size_t)i*DD, batch, t, gsum_i, N);
    norm1_kernel<<<nrmBlocks, 256, 0, stream>>>(t, gsum_i, cnt, batch, gn_ms+(size_t)i*DD, vsum_i, N);
    norm2_kernel<<<nrmBlocks, 256, 0, stream>>>(t, vsum_i, gsum_i, cnt, batch,
                                                gn_w+(size_t)i*DD, gn_b+(size_t)i*DD,
                                                gn_ms+(size_t)i*DD,
                                                h, hb, pout, (i>=2)?1:0, last, N);
  }
  finalize_kernel<<<16, 256, 0, stream>>>(pout, cnt, (float*)d_out);
}

// Round 10
// 887.135 us; speedup vs baseline: 1.7956x; 1.2469x over previous
//
#include <hip/hip_runtime.h>

#define DD 64
#define GG 64
#define EPSV 1e-5f
#define SLOPE 0.01f

#define AG_WAVES 8
#define AG_NPW 8
#define AG_NODES (AG_WAVES*AG_NPW) // 64 nodes per block (gemm kernel)
#define NRM_NPW 16

// binned CSR build
#define NRANGE 512
#define RSHIFT 8              // npr = 256 nodes per range (512*256 = 131072 >= N)
#define NPR 256
#define ABLK 512              // edge-chunk blocks in phases A1/A3

typedef unsigned short ushort_t;
typedef unsigned int uint_t;

__device__ __forceinline__ ushort_t f2bf(float f) {
  uint_t u = __float_as_uint(f);
  uint_t r = (u + 0x7fffu + ((u >> 16) & 1u)) >> 16;   // round-to-nearest-even
  return (ushort_t)r;
}
__device__ __forceinline__ float bf2f(ushort_t s) { return __uint_as_float(((uint_t)s) << 16); }
__device__ __forceinline__ float bflo(uint_t v) { return __uint_as_float(v << 16); }
__device__ __forceinline__ float bfhi(uint_t v) { return __uint_as_float(v & 0xffff0000u); }

// ---------- A1: per-(block,range) histograms, both directions, LDS-only atomics ----------
__global__ __launch_bounds__(256) void bin_count_kernel(const int* __restrict__ src,
                                                        const int* __restrict__ dst,
                                                        int* __restrict__ hist, int E) {
  __shared__ int cf[NRANGE], cb[NRANGE];
  for (int i=threadIdx.x; i<NRANGE; i+=256) { cf[i]=0; cb[i]=0; }
  __syncthreads();
  int epb = (E + ABLK-1)/ABLK;
  int lo = blockIdx.x*epb, hi = lo+epb; if (hi>E) hi=E;
  for (int e=lo+threadIdx.x; e<hi; e+=256) {
    int d = __builtin_nontemporal_load(&dst[e]);
    int s = __builtin_nontemporal_load(&src[e]);
    atomicAdd(&cf[d>>RSHIFT], 1);
    atomicAdd(&cb[s>>RSHIFT], 1);
  }
  __syncthreads();
  for (int r=threadIdx.x; r<NRANGE; r+=256) {
    hist[(size_t)r*ABLK + blockIdx.x]            = cf[r];
    hist[(size_t)(NRANGE+r)*ABLK + blockIdx.x]   = cb[r];
  }
}

// ---------- generic 2-level scan over hist (M = 2*NRANGE*ABLK = 524288) ----------
__global__ void block_sum_kernel(const int* __restrict__ v, int* __restrict__ partial, int M) {
  __shared__ int sm[1024];
  int i = blockIdx.x*1024 + threadIdx.x;
  sm[threadIdx.x] = (i<M) ? v[i] : 0;
  __syncthreads();
  for (int s=512; s>0; s>>=1) {
    if (threadIdx.x < s) sm[threadIdx.x] += sm[threadIdx.x+s];
    __syncthreads();
  }
  if (threadIdx.x==0) partial[blockIdx.x] = sm[0];
}

__global__ void scan_partial_kernel(int* __restrict__ partial, int nb) {  // 512 threads
  __shared__ int sm[512];
  int t = threadIdx.x;
  int v = (t<nb) ? partial[t] : 0;
  int orig = v;
  sm[t] = v; __syncthreads();
  for (int off=1; off<512; off<<=1) {
    int a = (t>=off) ? sm[t-off] : 0;
    __syncthreads();
    v += a; sm[t] = v;
    __syncthreads();
  }
  if (t<nb) partial[t] = v - orig;   // exclusive block offsets
}

__global__ void scan_apply_kernel(const int* __restrict__ v, const int* __restrict__ partial,
                                  int* __restrict__ out, int M) {
  __shared__ int sm[1024];
  int i = blockIdx.x*1024 + threadIdx.x;
  int x = (i<M) ? v[i] : 0;
  int orig = x;
  sm[threadIdx.x] = x; __syncthreads();
  for (int off=1; off<1024; off<<=1) {
    int a = (threadIdx.x>=off) ? sm[threadIdx.x-off] : 0;
    __syncthreads();
    x += a; sm[threadIdx.x] = x;
    __syncthreads();
  }
  if (i<M) out[i] = x - orig + partial[blockIdx.x];   // exclusive scan
}

// ---------- A3: scatter (key,val) records into reserved segments, LDS-only atomics ----------
__global__ __launch_bounds__(256) void bin_scatter_kernel(const int* __restrict__ src,
                                                          const int* __restrict__ dst,
                                                          const int* __restrict__ offs,
                                                          int2* __restrict__ staged, int E) {
  __shared__ int ofF[NRANGE], ofB[NRANGE];   // running write positions (LDS copies)
  for (int r=threadIdx.x; r<NRANGE; r+=256) {
    ofF[r] = offs[(size_t)r*ABLK + blockIdx.x];
    ofB[r] = offs[(size_t)(NRANGE+r)*ABLK + blockIdx.x];
  }
  __syncthreads();
  int epb = (E + ABLK-1)/ABLK;
  int lo = blockIdx.x*epb, hi = lo+epb; if (hi>E) hi=E;
  for (int e=lo+threadIdx.x; e<hi; e+=256) {
    int d = __builtin_nontemporal_load(&dst[e]);
    int s = __builtin_nontemporal_load(&src[e]);
    int pf = atomicAdd(&ofF[d>>RSHIFT], 1);
    staged[pf] = make_int2(d, s);              // fwd record: key=dst, val=src
    int pb = atomicAdd(&ofB[s>>RSHIFT], 1);
    staged[pb] = make_int2(s, d);              // bwd record: key=src, val=dst
  }
}

// ---------- B: per-range counting sort -> rp (coalesced) + col (L2-window scatter) ----------
__global__ __launch_bounds__(256) void range_fill_kernel(const int2* __restrict__ staged,
                                                         const int* __restrict__ offs,
                                                         int* __restrict__ rp_f, int* __restrict__ rp_b,
                                                         int* __restrict__ col_f, int* __restrict__ col_b,
                                                         int N, int E) {
  __shared__ int cnt[NPR], noff[NPR], sc[NPR];
  int lr = blockIdx.x;                // 0..2*NRANGE-1 ; d = lr>>9, r = lr&511
  int d = lr >> 9, r = lr & (NRANGE-1);
  int start = offs[(size_t)lr*ABLK];
  int end   = (lr+1 < 2*NRANGE) ? offs[(size_t)(lr+1)*ABLK] : 2*E;
  int t = threadIdx.x;
  cnt[t] = 0; __syncthreads();
  for (int k=start+t; k<end; k+=256) {
    int key = staged[k].x;
    atomicAdd(&cnt[key & (NPR-1)], 1);
  }
  __syncthreads();
  // exclusive scan cnt -> noff
  int x = cnt[t]; sc[t] = x; __syncthreads();
  for (int off=1; off<NPR; off<<=1) {
    int a = (t>=off) ? sc[t-off] : 0;
    __syncthreads();
    x += a; sc[t] = x;
    __syncthreads();
  }
  noff[t] = x - cnt[t];
  __syncthreads();
  int base = d ? (start - E) : start;
  int node = (r << RSHIFT) + t;
  int* rp = d ? rp_b : rp_f;
  if (node < N)       rp[node] = base + noff[t];
  else if (node == N) rp[N]    = base + noff[t];   // == E (all edges precede node N)
  cnt[t] = 0; __syncthreads();
  int* col = d ? col_b : col_f;
  for (int k=start+t; k<end; k+=256) {
    int2 rec = staged[k];
    int li = rec.x & (NPR-1);
    int rank = atomicAdd(&cnt[li], 1);
    col[base + noff[li] + rank] = rec.y;           // writes within ~16KB window
  }
}

__global__ void cnt_kernel(const int* __restrict__ batch, int* __restrict__ cnt, int N) {
  __shared__ int hist[GG];
  if (threadIdx.x < GG) hist[threadIdx.x] = 0;
  __syncthreads();
  int i = blockIdx.x*blockDim.x + threadIdx.x;
  int stride = gridDim.x*blockDim.x;
  for (int n=i; n<N; n+=stride) atomicAdd(&hist[batch[n]], 1);
  __syncthreads();
  if (threadIdx.x < GG) atomicAdd(&cnt[threadIdx.x], hist[threadIdx.x]);
}

// ----------------- fp32 -> bf16 shadow -----------------
__global__ void tobf16_kernel(const float* __restrict__ in, ushort_t* __restrict__ out, int M) {
  int i = blockIdx.x*blockDim.x + threadIdx.x;
  int stride = gridDim.x*blockDim.x;
  for (int k=i; k<M; k+=stride) out[k] = f2bf(in[k]);
}

// ----------------- gather: one wave per node, uint2 loads, bf16 sbuf out -----------------
__global__ __launch_bounds__(256) void gather_kernel(
    const ushort_t* __restrict__ hb,
    const int* __restrict__ rp_f, const int* __restrict__ col_f,
    const int* __restrict__ rp_b, const int* __restrict__ col_b,
    ushort_t* __restrict__ sbufb, int N)
{
  int w = (blockIdx.x*(blockDim.x>>6)) + (threadIdx.x>>6);   // node = global wave id
  if (w >= N) return;
  int lane = threadIdx.x & 63;
  int qt = lane >> 4;        // quarter 0..3
  int g  = lane & 15;        // feature quad: features 4g..4g+3
  const uint2* hbp = (const uint2*)hb;

  float f0=0.f,f1=0.f,f2=0.f,f3=0.f, b0=0.f,b1=0.f,b2=0.f,b3=0.f;
  int degf, degb;

  {
    int s0 = rp_f[w], e0 = rp_f[w+1];
    degf = e0 - s0;
    for (int base=s0; base<e0; base+=64) {
      int m = e0-base; if (m>64) m=64;
      int jv = (lane<m) ? col_f[base+lane] : 0;
      int q=0;
      for (; 4*q+16 <= m; q+=4) {
        int j0=__shfl(jv,4*q+qt),    j1=__shfl(jv,4*q+4+qt);
        int j2=__shfl(jv,4*q+8+qt),  j3=__shfl(jv,4*q+12+qt);
        uint2 v0=hbp[(size_t)j0*16+g], v1=hbp[(size_t)j1*16+g];
        uint2 v2=hbp[(size_t)j2*16+g], v3=hbp[(size_t)j3*16+g];
        f0 += (bflo(v0.x)+bflo(v1.x))+(bflo(v2.x)+bflo(v3.x));
        f1 += (bfhi(v0.x)+bfhi(v1.x))+(bfhi(v2.x)+bfhi(v3.x));
        f2 += (bflo(v0.y)+bflo(v1.y))+(bflo(v2.y)+bflo(v3.y));
        f3 += (bfhi(v0.y)+bfhi(v1.y))+(bfhi(v2.y)+bfhi(v3.y));
      }
      for (; 4*q+qt < m; ++q) {
        int j=__shfl(jv,4*q+qt);
        uint2 v=hbp[(size_t)j*16+g];
        f0+=bflo(v.x); f1+=bfhi(v.x); f2+=bflo(v.y); f3+=bfhi(v.y);
      }
    }
  }
  {
    int s1 = rp_b[w], e1 = rp_b[w+1];
    degb = e1 - s1;
    for (int base=s1; base<e1; base+=64) {
      int m = e1-base; if (m>64) m=64;
      int jv = (lane<m) ? col_b[base+lane] : 0;
      int q=0;
      for (; 4*q+16 <= m; q+=4) {
        int j0=__shfl(jv,4*q+qt),    j1=__shfl(jv,4*q+4+qt);
        int j2=__shfl(jv,4*q+8+qt),  j3=__shfl(jv,4*q+12+qt);
        uint2 v0=hbp[(size_t)j0*16+g], v1=hbp[(size_t)j1*16+g];
        uint2 v2=hbp[(size_t)j2*16+g], v3=hbp[(size_t)j3*16+g];
        b0 += (bflo(v0.x)+bflo(v1.x))+(bflo(v2.x)+bflo(v3.x));
        b1 += (bfhi(v0.x)+bfhi(v1.x))+(bfhi(v2.x)+bfhi(v3.x));
        b2 += (bflo(v0.y)+bflo(v1.y))+(bflo(v2.y)+bflo(v3.y));
        b3 += (bfhi(v0.y)+bfhi(v1.y))+(bfhi(v2.y)+bfhi(v3.y));
      }
      for (; 4*q+qt < m; ++q) {
        int j=__shfl(jv,4*q+qt);
        uint2 v=hbp[(size_t)j*16+g];
        b0+=bflo(v.x); b1+=bfhi(v.x); b2+=bflo(v.y); b3+=bfhi(v.y);
      }
    }
  }

  float df = fmaxf((float)degf, 1.f);
  float db = fmaxf((float)degb, 1.f);
  float s0v = 0.5f*(f0/df + b0/db);
  float s1v = 0.5f*(f1/df + b1/db);
  float s2v = 0.5f*(f2/df + b2/db);
  float s3v = 0.5f*(f3/df + b3/db);
  s0v += __shfl_xor(s0v,16); s0v += __shfl_xor(s0v,32);
  s1v += __shfl_xor(s1v,16); s1v += __shfl_xor(s1v,32);
  s2v += __shfl_xor(s2v,16); s2v += __shfl_xor(s2v,32);
  s3v += __shfl_xor(s3v,16); s3v += __shfl_xor(s3v,32);
  if (qt==0) {
    uint_t p0 = (uint_t)f2bf(s0v) | ((uint_t)f2bf(s1v) << 16);
    uint_t p1 = (uint_t)f2bf(s2v) | ((uint_t)f2bf(s3v) << 16);
    *(uint2*)&((uint_t*)sbufb)[(size_t)w*32 + 2*g] = make_uint2(p0, p1);
  }
}

// ----------------- dual GEMM + graph sum & sum-of-squares (streaming, bf16 in) -----------------
__global__ __launch_bounds__(512) void gemm_kernel(
    const ushort_t* __restrict__ hb, const ushort_t* __restrict__ sbufb,
    const float* __restrict__ Wl, const float* __restrict__ Wr, const float* __restrict__ bias,
    const int* __restrict__ batch,
    float* __restrict__ t, float* __restrict__ gsum, float* __restrict__ gsq, int N)
{
  __shared__ float srow[AG_NODES][DD];
  __shared__ float hrow[AG_NODES][DD];

  int wid = threadIdx.x >> 6;
  int lane = threadIdx.x & 63;
  int nodeBase = blockIdx.x*AG_NODES + wid*AG_NPW;

  for (int nn=0; nn<AG_NPW; ++nn) {
    int node = nodeBase + nn;
    float sval = 0.f, hval = 0.f;
    if (node < N) {
      sval = bf2f(sbufb[(size_t)node*DD+lane]);
      hval = bf2f(hb[(size_t)node*DD+lane]);
    }
    srow[wid*AG_NPW+nn][lane] = sval;
    hrow[wid*AG_NPW+nn][lane] = hval;
  }
  // no barrier: each wave reads only its own 8 rows

  float bv = bias[lane];
  float tacc[AG_NPW];
  #pragma unroll
  for (int nn=0; nn<AG_NPW; ++nn) tacc[nn]=bv;

  for (int k=0; k<DD; k+=4) {
    float w0 = Wl[(k+0)*DD+lane], w1 = Wl[(k+1)*DD+lane];
    float w2 = Wl[(k+2)*DD+lane], w3 = Wl[(k+3)*DD+lane];
    float r0 = Wr[(k+0)*DD+lane], r1 = Wr[(k+1)*DD+lane];
    float r2 = Wr[(k+2)*DD+lane], r3 = Wr[(k+3)*DD+lane];
    #pragma unroll
    for (int nn=0; nn<AG_NPW; ++nn) {
      float4 sv = *(const float4*)&srow[wid*AG_NPW+nn][k];
      float4 hv = *(const float4*)&hrow[wid*AG_NPW+nn][k];
      tacc[nn] += sv.x*w0 + sv.y*w1 + sv.z*w2 + sv.w*w3
                + hv.x*r0 + hv.y*r1 + hv.z*r2 + hv.w*r3;
    }
  }

  int gcur = -1; float gacc = 0.f, qacc = 0.f;
  for (int nn=0; nn<AG_NPW; ++nn) {
    int node = nodeBase+nn;
    if (node >= N) break;
    t[(size_t)node*DD+lane] = tacc[nn];
    int g = batch[node];
    if (g != gcur) {
      if (gcur >= 0) {
        atomicAdd(&gsum[gcur*DD+lane], gacc);
        atomicAdd(&gsq[gcur*DD+lane], qacc);
      }
      gcur = g; gacc = 0.f; qacc = 0.f;
    }
    gacc += tacc[nn];
    qacc += tacc[nn]*tacc[nn];
  }
  if (gcur >= 0) {
    atomicAdd(&gsum[gcur*DD+lane], gacc);
    atomicAdd(&gsq[gcur*DD+lane], qacc);
  }
}

// -------- GraphNorm (single pass; var from sums) + leaky + residual; last fuses pool --------
__global__ void norm2_kernel(const float* __restrict__ t,
                             const float* __restrict__ gsum, const float* __restrict__ gsq,
                             const int* __restrict__ cnt, const int* __restrict__ batch,
                             const float* __restrict__ gw, const float* __restrict__ gb,
                             const float* __restrict__ gms,
                             float* __restrict__ h, ushort_t* __restrict__ hb,
                             float* __restrict__ pout,
                             int resid, int last, int N)
{
  int wid = (blockIdx.x*blockDim.x + threadIdx.x) >> 6;
  int lane = threadIdx.x & 63;
  int base = wid*NRM_NPW;
  if (base >= N) return;
  float wv = gw[lane], bv = gb[lane], msv = gms[lane];
  float cms = msv*(2.f - msv);
  int gcur=-1; float rs=0.f, mean=0.f, pacc=0.f;
  int end = base+NRM_NPW; if (end>N) end=N;
  for (int node=base; node<end; ++node) {
    int g = batch[node];
    if (g!=gcur) {
      if (last && gcur>=0) atomicAdd(&pout[gcur*DD+lane], pacc);
      pacc = 0.f;
      float invc = 1.f/fmaxf((float)cnt[g],1.f);
      mean = gsum[g*DD+lane]*invc;
      float msq = gsq[g*DD+lane]*invc;
      float var = msq - cms*mean*mean;         // E[(t-ms*mean)^2]
      rs = rsqrtf(var + EPSV);
      gcur=g;
    }
    float u = t[(size_t)node*DD+lane] - msv*mean;
    float y = wv*u*rs + bv;
    y = (y>=0.f) ? y : SLOPE*y;
    float hv = resid ? (h[(size_t)node*DD+lane] + y) : y;
    if (last) {
      pacc += hv;
    } else {
      h[(size_t)node*DD+lane] = hv;
      hb[(size_t)node*DD+lane] = f2bf(hv);
    }
  }
  if (last && gcur>=0) atomicAdd(&pout[gcur*DD+lane], pacc);
}

__global__ void finalize_kernel(const float* __restrict__ pout, const int* __restrict__ cnt,
                                float* __restrict__ out)
{
  int i = blockIdx.x*blockDim.x + threadIdx.x;
  if (i < GG*DD) {
    float invc = 1.f/fmaxf((float)cnt[i>>6],1.f);
    out[i] = pout[i]*invc;
  }
}

extern "C" void kernel_launch(void* const* d_in, const int* in_sizes, int n_in,
                              void* d_out, int out_size, void* d_ws, size_t ws_size,
                              hipStream_t stream)
{
  const float* x    = (const float*)d_in[0];
  const int*  ei    = (const int*)d_in[1];
  const int*  batch = (const int*)d_in[2];
  const float* W_l  = (const float*)d_in[3];
  const float* W_r  = (const float*)d_in[4];
  const float* bias = (const float*)d_in[5];
  const float* gn_w = (const float*)d_in[6];
  const float* gn_b = (const float*)d_in[7];
  const float* gn_ms= (const float*)d_in[8];

  int N = in_sizes[2];
  int E = in_sizes[1]/2;
  int L = in_sizes[5]/DD;
  const int* src = ei;
  const int* dst = ei + E;

  // ---- workspace layout: zero-zone first (single memset) ----
  char* p = (char*)d_ws;
  int*   cnt   = (int*)p;   p += GG*4;
  float* gsum  = (float*)p; p += (size_t)L*GG*DD*4;
  float* gsq   = (float*)p; p += (size_t)L*GG*DD*4;
  float* pout  = (float*)p; p += GG*DD*4;
  size_t zeroBytes = (char*)p - (char*)d_ws;

  float* h     = (float*)p; p += (size_t)N*DD*4;
  float* t     = (float*)p; p += (size_t)N*DD*4;      // ALIASED as staged during CSR build
  ushort_t* sbufb = (ushort_t*)p; p += (size_t)N*DD*2;
  ushort_t* hb    = (ushort_t*)p; p += (size_t)N*DD*2;
  int* rp_f    = (int*)p; p += (size_t)(N+1)*4;
  int* rp_b    = (int*)p; p += (size_t)(N+1)*4;
  int* col_f   = (int*)p; p += (size_t)E*4;
  int* col_b   = (int*)p; p += (size_t)E*4;
  int* hist    = (int*)p; p += (size_t)2*NRANGE*ABLK*4;   // 2MB
  int* offs    = (int*)p; p += (size_t)2*NRANGE*ABLK*4;   // 2MB
  int* partial = (int*)p; p += 512*4;

  int2* staged = (int2*)t;      // 2E*8 == N*DD*4 bytes

  hipMemsetAsync(d_ws, 0, zeroBytes, stream);

  const int M = 2*NRANGE*ABLK;  // 524288
  bin_count_kernel<<<ABLK, 256, 0, stream>>>(src, dst, hist, E);
  block_sum_kernel<<<(M+1023)/1024, 1024, 0, stream>>>(hist, partial, M);
  scan_partial_kernel<<<1, 512, 0, stream>>>(partial, (M+1023)/1024);
  scan_apply_kernel<<<(M+1023)/1024, 1024, 0, stream>>>(hist, partial, offs, M);
  bin_scatter_kernel<<<ABLK, 256, 0, stream>>>(src, dst, offs, staged, E);
  range_fill_kernel<<<2*NRANGE, 256, 0, stream>>>(staged, offs, rp_f, rp_b, col_f, col_b, N, E);

  cnt_kernel<<<391, 256, 0, stream>>>(batch, cnt, N);
  tobf16_kernel<<<2048, 256, 0, stream>>>(x, hb, N*DD);

  int gthBlocks = (N + 3)/4;           // 4 waves (nodes) per 256-thread block
  int agBlocks = (N + AG_NODES-1)/AG_NODES;
  int nrmWaves = (N + NRM_NPW-1)/NRM_NPW;
  int nrmBlocks = (nrmWaves+3)/4;

  for (int i=0; i<L; ++i) {
    float* gsum_i = gsum + (size_t)i*GG*DD;
    float* gsq_i  = gsq  + (size_t)i*GG*DD;
    int last = (i==L-1) ? 1 : 0;
    gather_kernel<<<gthBlocks, 256, 0, stream>>>(hb, rp_f, col_f, rp_b, col_b, sbufb, N);
    gemm_kernel<<<agBlocks, 512, 0, stream>>>(hb, sbufb,
                                              W_l+(size_t)i*DD*DD, W_r+(size_t)i*DD*DD,
                                              bias+(size_t)i*DD, batch, t, gsum_i, gsq_i, N);
    norm2_kernel<<<nrmBlocks, 256, 0, stream>>>(t, gsum_i, gsq_i, cnt, batch,
                                                gn_w+(size_t)i*DD, gn_b+(size_t)i*DD,
                                                gn_ms+(size_t)i*DD,
                                                h, hb, pout, (i>=2)?1:0, last, N);
  }
  finalize_kernel<<<16, 256, 0, stream>>>(pout, cnt, (float*)d_out);
}

// Round 11
// 872.361 us; speedup vs baseline: 1.8260x; 1.0169x over previous
//
#include <hip/hip_runtime.h>

#define DD 64
#define GG 64
#define EPSV 1e-5f
#define SLOPE 0.01f

#define AG_WAVES 8
#define AG_NPW 8
#define AG_NODES (AG_WAVES*AG_NPW) // 64 nodes per block (gemm kernel)
#define NRM_NPW 16

// binned CSR build
#define NRANGE 512
#define RSHIFT 8              // 256 nodes per range (512*256 = 131072 >= N)
#define NPR 256
#define ABLK 512              // edge-chunk blocks in phases A1/A3

typedef unsigned short ushort_t;
typedef unsigned int uint_t;
typedef float v2f __attribute__((ext_vector_type(2)));

__device__ __forceinline__ ushort_t f2bf(float f) {
  uint_t u = __float_as_uint(f);
  uint_t r = (u + 0x7fffu + ((u >> 16) & 1u)) >> 16;   // round-to-nearest-even
  return (ushort_t)r;
}
__device__ __forceinline__ float bf2f(ushort_t s) { return __uint_as_float(((uint_t)s) << 16); }
__device__ __forceinline__ v2f unpk(uint_t u) {      // {lo,hi} bf16 pair -> 2 floats
  v2f r;
  r.x = __uint_as_float(u << 16);
  r.y = __uint_as_float(u & 0xffff0000u);
  return r;                                           // acc += unpk() -> v_pk_add_f32
}

// ---------- A1: per-(block,range) histograms, both directions, LDS-only atomics ----------
__global__ __launch_bounds__(256) void bin_count_kernel(const int* __restrict__ src,
                                                        const int* __restrict__ dst,
                                                        int* __restrict__ hist, int E) {
  __shared__ int cf[NRANGE], cb[NRANGE];
  for (int i=threadIdx.x; i<NRANGE; i+=256) { cf[i]=0; cb[i]=0; }
  __syncthreads();
  int epb = (E + ABLK-1)/ABLK;
  int lo = blockIdx.x*epb, hi = lo+epb; if (hi>E) hi=E;
  for (int e=lo+threadIdx.x; e<hi; e+=256) {
    int d = __builtin_nontemporal_load(&dst[e]);
    int s = __builtin_nontemporal_load(&src[e]);
    atomicAdd(&cf[d>>RSHIFT], 1);
    atomicAdd(&cb[s>>RSHIFT], 1);
  }
  __syncthreads();
  for (int r=threadIdx.x; r<NRANGE; r+=256) {
    hist[(size_t)r*ABLK + blockIdx.x]            = cf[r];
    hist[(size_t)(NRANGE+r)*ABLK + blockIdx.x]   = cb[r];
  }
}

// ---------- generic 2-level scan over hist (M = 2*NRANGE*ABLK = 524288) ----------
__global__ void block_sum_kernel(const int* __restrict__ v, int* __restrict__ partial, int M) {
  __shared__ int sm[1024];
  int i = blockIdx.x*1024 + threadIdx.x;
  sm[threadIdx.x] = (i<M) ? v[i] : 0;
  __syncthreads();
  for (int s=512; s>0; s>>=1) {
    if (threadIdx.x < s) sm[threadIdx.x] += sm[threadIdx.x+s];
    __syncthreads();
  }
  if (threadIdx.x==0) partial[blockIdx.x] = sm[0];
}

__global__ void scan_partial_kernel(int* __restrict__ partial, int nb) {  // 512 threads
  __shared__ int sm[512];
  int t = threadIdx.x;
  int v = (t<nb) ? partial[t] : 0;
  int orig = v;
  sm[t] = v; __syncthreads();
  for (int off=1; off<512; off<<=1) {
    int a = (t>=off) ? sm[t-off] : 0;
    __syncthreads();
    v += a; sm[t] = v;
    __syncthreads();
  }
  if (t<nb) partial[t] = v - orig;   // exclusive block offsets
}

__global__ void scan_apply_kernel(const int* __restrict__ v, const int* __restrict__ partial,
                                  int* __restrict__ out, int M) {
  __shared__ int sm[1024];
  int i = blockIdx.x*1024 + threadIdx.x;
  int x = (i<M) ? v[i] : 0;
  int orig = x;
  sm[threadIdx.x] = x; __syncthreads();
  for (int off=1; off<1024; off<<=1) {
    int a = (threadIdx.x>=off) ? sm[threadIdx.x-off] : 0;
    __syncthreads();
    x += a; sm[threadIdx.x] = x;
    __syncthreads();
  }
  if (i<M) out[i] = x - orig + partial[blockIdx.x];   // exclusive scan
}

// ---------- A3: scatter (key,val) records into reserved segments, LDS-only atomics ----------
__global__ __launch_bounds__(256) void bin_scatter_kernel(const int* __restrict__ src,
                                                          const int* __restrict__ dst,
                                                          const int* __restrict__ offs,
                                                          int2* __restrict__ staged, int E) {
  __shared__ int ofF[NRANGE], ofB[NRANGE];
  for (int r=threadIdx.x; r<NRANGE; r+=256) {
    ofF[r] = offs[(size_t)r*ABLK + blockIdx.x];
    ofB[r] = offs[(size_t)(NRANGE+r)*ABLK + blockIdx.x];
  }
  __syncthreads();
  int epb = (E + ABLK-1)/ABLK;
  int lo = blockIdx.x*epb, hi = lo+epb; if (hi>E) hi=E;
  for (int e=lo+threadIdx.x; e<hi; e+=256) {
    int d = __builtin_nontemporal_load(&dst[e]);
    int s = __builtin_nontemporal_load(&src[e]);
    int pf = atomicAdd(&ofF[d>>RSHIFT], 1);
    staged[pf] = make_int2(d, s);              // fwd record: key=dst, val=src
    int pb = atomicAdd(&ofB[s>>RSHIFT], 1);
    staged[pb] = make_int2(s, d);              // bwd record: key=src, val=dst
  }
}

// ---------- B: per-range counting sort -> rp (coalesced) + col (L2-window scatter) ----------
__global__ __launch_bounds__(256) void range_fill_kernel(const int2* __restrict__ staged,
                                                         const int* __restrict__ offs,
                                                         int* __restrict__ rp_f, int* __restrict__ rp_b,
                                                         int* __restrict__ col_f, int* __restrict__ col_b,
                                                         int N, int E) {
  __shared__ int cnt[NPR], noff[NPR], sc[NPR];
  int lr = blockIdx.x;
  int d = lr >> 9, r = lr & (NRANGE-1);
  int start = offs[(size_t)lr*ABLK];
  int end   = (lr+1 < 2*NRANGE) ? offs[(size_t)(lr+1)*ABLK] : 2*E;
  int t = threadIdx.x;
  cnt[t] = 0; __syncthreads();
  for (int k=start+t; k<end; k+=256) {
    int key = staged[k].x;
    atomicAdd(&cnt[key & (NPR-1)], 1);
  }
  __syncthreads();
  int x = cnt[t]; sc[t] = x; __syncthreads();
  for (int off=1; off<NPR; off<<=1) {
    int a = (t>=off) ? sc[t-off] : 0;
    __syncthreads();
    x += a; sc[t] = x;
    __syncthreads();
  }
  noff[t] = x - cnt[t];
  __syncthreads();
  int base = d ? (start - E) : start;
  int node = (r << RSHIFT) + t;
  int* rp = d ? rp_b : rp_f;
  if (node < N)       rp[node] = base + noff[t];
  else if (node == N) rp[N]    = base + noff[t];
  cnt[t] = 0; __syncthreads();
  int* col = d ? col_b : col_f;
  for (int k=start+t; k<end; k+=256) {
    int2 rec = staged[k];
    int li = rec.x & (NPR-1);
    int rank = atomicAdd(&cnt[li], 1);
    col[base + noff[li] + rank] = rec.y;
  }
}

__global__ void cnt_kernel(const int* __restrict__ batch, int* __restrict__ cnt, int N) {
  __shared__ int hist[GG];
  if (threadIdx.x < GG) hist[threadIdx.x] = 0;
  __syncthreads();
  int i = blockIdx.x*blockDim.x + threadIdx.x;
  int stride = gridDim.x*blockDim.x;
  for (int n=i; n<N; n+=stride) atomicAdd(&hist[batch[n]], 1);
  __syncthreads();
  if (threadIdx.x < GG) atomicAdd(&cnt[threadIdx.x], hist[threadIdx.x]);
}

// ----------------- fp32 -> bf16 shadow -----------------
__global__ void tobf16_kernel(const float* __restrict__ in, ushort_t* __restrict__ out, int M) {
  int i = blockIdx.x*blockDim.x + threadIdx.x;
  int stride = gridDim.x*blockDim.x;
  for (int k=i; k<M; k+=stride) out[k] = f2bf(in[k]);
}

// ----------------- gather: one wave per node; 32-bit offsets + packed accumulate --------
__global__ __launch_bounds__(256) void gather_kernel(
    const ushort_t* __restrict__ hb,
    const int* __restrict__ rp_f, const int* __restrict__ col_f,
    const int* __restrict__ rp_b, const int* __restrict__ col_b,
    ushort_t* __restrict__ sbufb, int N)
{
  int w = (blockIdx.x*(blockDim.x>>6)) + (threadIdx.x>>6);   // node = global wave id
  if (w >= N) return;
  int lane = threadIdx.x & 63;
  int qt = lane >> 4;        // quarter 0..3
  int g  = lane & 15;        // feature quad: features 4g..4g+3
  const char* hbb = (const char*)hb;
  uint_t goff = (uint_t)g << 3;     // byte offset of this lane's quad within a row

  v2f a01={0.f,0.f}, a23={0.f,0.f}, c01={0.f,0.f}, c23={0.f,0.f};
  int degf, degb;

  {
    int s0 = rp_f[w], e0 = rp_f[w+1];
    degf = e0 - s0;
    for (int base=s0; base<e0; base+=64) {
      int m = e0-base; if (m>64) m=64;
      int jv = (lane<m) ? col_f[base+lane] : 0;
      int q=0;
      for (; 4*q+16 <= m; q+=4) {
        int j0=__shfl(jv,4*q+qt),    j1=__shfl(jv,4*q+4+qt);
        int j2=__shfl(jv,4*q+8+qt),  j3=__shfl(jv,4*q+12+qt);
        uint2 v0 = *(const uint2*)(hbb + ((((uint_t)j0)<<7) | goff));
        uint2 v1 = *(const uint2*)(hbb + ((((uint_t)j1)<<7) | goff));
        uint2 v2 = *(const uint2*)(hbb + ((((uint_t)j2)<<7) | goff));
        uint2 v3 = *(const uint2*)(hbb + ((((uint_t)j3)<<7) | goff));
        a01 += unpk(v0.x); a23 += unpk(v0.y);
        a01 += unpk(v1.x); a23 += unpk(v1.y);
        a01 += unpk(v2.x); a23 += unpk(v2.y);
        a01 += unpk(v3.x); a23 += unpk(v3.y);
      }
      for (; 4*q+qt < m; ++q) {
        int j=__shfl(jv,4*q+qt);
        uint2 v = *(const uint2*)(hbb + ((((uint_t)j)<<7) | goff));
        a01 += unpk(v.x); a23 += unpk(v.y);
      }
    }
  }
  {
    int s1 = rp_b[w], e1 = rp_b[w+1];
    degb = e1 - s1;
    for (int base=s1; base<e1; base+=64) {
      int m = e1-base; if (m>64) m=64;
      int jv = (lane<m) ? col_b[base+lane] : 0;
      int q=0;
      for (; 4*q+16 <= m; q+=4) {
        int j0=__shfl(jv,4*q+qt),    j1=__shfl(jv,4*q+4+qt);
        int j2=__shfl(jv,4*q+8+qt),  j3=__shfl(jv,4*q+12+qt);
        uint2 v0 = *(const uint2*)(hbb + ((((uint_t)j0)<<7) | goff));
        uint2 v1 = *(const uint2*)(hbb + ((((uint_t)j1)<<7) | goff));
        uint2 v2 = *(const uint2*)(hbb + ((((uint_t)j2)<<7) | goff));
        uint2 v3 = *(const uint2*)(hbb + ((((uint_t)j3)<<7) | goff));
        c01 += unpk(v0.x); c23 += unpk(v0.y);
        c01 += unpk(v1.x); c23 += unpk(v1.y);
        c01 += unpk(v2.x); c23 += unpk(v2.y);
        c01 += unpk(v3.x); c23 += unpk(v3.y);
      }
      for (; 4*q+qt < m; ++q) {
        int j=__shfl(jv,4*q+qt);
        uint2 v = *(const uint2*)(hbb + ((((uint_t)j)<<7) | goff));
        c01 += unpk(v.x); c23 += unpk(v.y);
      }
    }
  }

  float df = fmaxf((float)degf, 1.f);
  float db = fmaxf((float)degb, 1.f);
  float s0v = 0.5f*(a01.x/df + c01.x/db);
  float s1v = 0.5f*(a01.y/df + c01.y/db);
  float s2v = 0.5f*(a23.x/df + c23.x/db);
  float s3v = 0.5f*(a23.y/df + c23.y/db);
  s0v += __shfl_xor(s0v,16); s0v += __shfl_xor(s0v,32);
  s1v += __shfl_xor(s1v,16); s1v += __shfl_xor(s1v,32);
  s2v += __shfl_xor(s2v,16); s2v += __shfl_xor(s2v,32);
  s3v += __shfl_xor(s3v,16); s3v += __shfl_xor(s3v,32);
  if (qt==0) {
    uint_t p0 = (uint_t)f2bf(s0v) | ((uint_t)f2bf(s1v) << 16);
    uint_t p1 = (uint_t)f2bf(s2v) | ((uint_t)f2bf(s3v) << 16);
    *(uint2*)&((uint_t*)sbufb)[(size_t)w*32 + 2*g] = make_uint2(p0, p1);
  }
}

// --------- dual GEMM + graph sum & sum-of-squares (bf16 in, bf16 t out) ---------
__global__ __launch_bounds__(512) void gemm_kernel(
    const ushort_t* __restrict__ hb, const ushort_t* __restrict__ sbufb,
    const float* __restrict__ Wl, const float* __restrict__ Wr, const float* __restrict__ bias,
    const int* __restrict__ batch,
    ushort_t* __restrict__ tb, float* __restrict__ gsum, float* __restrict__ gsq, int N)
{
  __shared__ float srow[AG_NODES][DD];
  __shared__ float hrow[AG_NODES][DD];

  int wid = threadIdx.x >> 6;
  int lane = threadIdx.x & 63;
  int nodeBase = blockIdx.x*AG_NODES + wid*AG_NPW;

  for (int nn=0; nn<AG_NPW; ++nn) {
    int node = nodeBase + nn;
    float sval = 0.f, hval = 0.f;
    if (node < N) {
      sval = bf2f(sbufb[(size_t)node*DD+lane]);
      hval = bf2f(hb[(size_t)node*DD+lane]);
    }
    srow[wid*AG_NPW+nn][lane] = sval;
    hrow[wid*AG_NPW+nn][lane] = hval;
  }
  // no barrier: each wave reads only its own 8 rows

  float bv = bias[lane];
  float tacc[AG_NPW];
  #pragma unroll
  for (int nn=0; nn<AG_NPW; ++nn) tacc[nn]=bv;

  for (int k=0; k<DD; k+=4) {
    float w0 = Wl[(k+0)*DD+lane], w1 = Wl[(k+1)*DD+lane];
    float w2 = Wl[(k+2)*DD+lane], w3 = Wl[(k+3)*DD+lane];
    float r0 = Wr[(k+0)*DD+lane], r1 = Wr[(k+1)*DD+lane];
    float r2 = Wr[(k+2)*DD+lane], r3 = Wr[(k+3)*DD+lane];
    #pragma unroll
    for (int nn=0; nn<AG_NPW; ++nn) {
      float4 sv = *(const float4*)&srow[wid*AG_NPW+nn][k];
      float4 hv = *(const float4*)&hrow[wid*AG_NPW+nn][k];
      tacc[nn] += sv.x*w0 + sv.y*w1 + sv.z*w2 + sv.w*w3
                + hv.x*r0 + hv.y*r1 + hv.z*r2 + hv.w*r3;
    }
  }

  int gcur = -1; float gacc = 0.f, qacc = 0.f;
  for (int nn=0; nn<AG_NPW; ++nn) {
    int node = nodeBase+nn;
    if (node >= N) break;
    tb[(size_t)node*DD+lane] = f2bf(tacc[nn]);
    int g = batch[node];
    if (g != gcur) {
      if (gcur >= 0) {
        atomicAdd(&gsum[gcur*DD+lane], gacc);
        atomicAdd(&gsq[gcur*DD+lane], qacc);
      }
      gcur = g; gacc = 0.f; qacc = 0.f;
    }
    gacc += tacc[nn];
    qacc += tacc[nn]*tacc[nn];
  }
  if (gcur >= 0) {
    atomicAdd(&gsum[gcur*DD+lane], gacc);
    atomicAdd(&gsq[gcur*DD+lane], qacc);
  }
}

// ---- GraphNorm (var from sums) + leaky + residual, bf16 state in-place; last fuses pool ----
__global__ void norm2_kernel(const ushort_t* __restrict__ tb,
                             const float* __restrict__ gsum, const float* __restrict__ gsq,
                             const int* __restrict__ cnt, const int* __restrict__ batch,
                             const float* __restrict__ gw, const float* __restrict__ gb,
                             const float* __restrict__ gms,
                             ushort_t* __restrict__ hb,
                             float* __restrict__ pout,
                             int resid, int last, int N)
{
  int wid = (blockIdx.x*blockDim.x + threadIdx.x) >> 6;
  int lane = threadIdx.x & 63;
  int base = wid*NRM_NPW;
  if (base >= N) return;
  float wv = gw[lane], bv = gb[lane], msv = gms[lane];
  float cms = msv*(2.f - msv);
  int gcur=-1; float rs=0.f, mean=0.f, pacc=0.f;
  int end = base+NRM_NPW; if (end>N) end=N;
  for (int node=base; node<end; ++node) {
    int g = batch[node];
    if (g!=gcur) {
      if (last && gcur>=0) atomicAdd(&pout[gcur*DD+lane], pacc);
      pacc = 0.f;
      float invc = 1.f/fmaxf((float)cnt[g],1.f);
      mean = gsum[g*DD+lane]*invc;
      float msq = gsq[g*DD+lane]*invc;
      float var = msq - cms*mean*mean;         // E[(t-ms*mean)^2]
      rs = rsqrtf(var + EPSV);
      gcur=g;
    }
    float u = bf2f(tb[(size_t)node*DD+lane]) - msv*mean;
    float y = wv*u*rs + bv;
    y = (y>=0.f) ? y : SLOPE*y;
    float hv = resid ? (bf2f(hb[(size_t)node*DD+lane]) + y) : y;
    if (last) {
      pacc += hv;                  // final h never re-read: pool only
    } else {
      hb[(size_t)node*DD+lane] = f2bf(hv);   // in-place: all layer-i readers done
    }
  }
  if (last && gcur>=0) atomicAdd(&pout[gcur*DD+lane], pacc);
}

__global__ void finalize_kernel(const float* __restrict__ pout, const int* __restrict__ cnt,
                                float* __restrict__ out)
{
  int i = blockIdx.x*blockDim.x + threadIdx.x;
  if (i < GG*DD) {
    float invc = 1.f/fmaxf((float)cnt[i>>6],1.f);
    out[i] = pout[i]*invc;
  }
}

extern "C" void kernel_launch(void* const* d_in, const int* in_sizes, int n_in,
                              void* d_out, int out_size, void* d_ws, size_t ws_size,
                              hipStream_t stream)
{
  const float* x    = (const float*)d_in[0];
  const int*  ei    = (const int*)d_in[1];
  const int*  batch = (const int*)d_in[2];
  const float* W_l  = (const float*)d_in[3];
  const float* W_r  = (const float*)d_in[4];
  const float* bias = (const float*)d_in[5];
  const float* gn_w = (const float*)d_in[6];
  const float* gn_b = (const float*)d_in[7];
  const float* gn_ms= (const float*)d_in[8];

  int N = in_sizes[2];
  int E = in_sizes[1]/2;
  int L = in_sizes[5]/DD;
  const int* src = ei;
  const int* dst = ei + E;

  // ---- workspace layout: zero-zone first (single memset) ----
  char* p = (char*)d_ws;
  int*   cnt   = (int*)p;   p += GG*4;
  float* gsum  = (float*)p; p += (size_t)L*GG*DD*4;
  float* gsq   = (float*)p; p += (size_t)L*GG*DD*4;
  float* pout  = (float*)p; p += GG*DD*4;
  size_t zeroBytes = (char*)p - (char*)d_ws;

  int2* staged = (int2*)p; p += (size_t)2*E*8;            // CSR build records (25.6MB)
  ushort_t* tb    = (ushort_t*)p; p += (size_t)N*DD*2;
  ushort_t* sbufb = (ushort_t*)p; p += (size_t)N*DD*2;
  ushort_t* hb    = (ushort_t*)p; p += (size_t)N*DD*2;
  int* rp_f    = (int*)p; p += (size_t)(N+1)*4;
  int* rp_b    = (int*)p; p += (size_t)(N+1)*4;
  int* col_f   = (int*)p; p += (size_t)E*4;
  int* col_b   = (int*)p; p += (size_t)E*4;
  int* hist    = (int*)p; p += (size_t)2*NRANGE*ABLK*4;   // 2MB
  int* offs    = (int*)p; p += (size_t)2*NRANGE*ABLK*4;   // 2MB
  int* partial = (int*)p; p += 512*4;

  hipMemsetAsync(d_ws, 0, zeroBytes, stream);

  const int M = 2*NRANGE*ABLK;  // 524288
  bin_count_kernel<<<ABLK, 256, 0, stream>>>(src, dst, hist, E);
  block_sum_kernel<<<(M+1023)/1024, 1024, 0, stream>>>(hist, partial, M);
  scan_partial_kernel<<<1, 512, 0, stream>>>(partial, (M+1023)/1024);
  scan_apply_kernel<<<(M+1023)/1024, 1024, 0, stream>>>(hist, partial, offs, M);
  bin_scatter_kernel<<<ABLK, 256, 0, stream>>>(src, dst, offs, staged, E);
  range_fill_kernel<<<2*NRANGE, 256, 0, stream>>>(staged, offs, rp_f, rp_b, col_f, col_b, N, E);

  cnt_kernel<<<391, 256, 0, stream>>>(batch, cnt, N);
  tobf16_kernel<<<2048, 256, 0, stream>>>(x, hb, N*DD);

  int gthBlocks = (N + 3)/4;           // 4 waves (nodes) per 256-thread block
  int agBlocks = (N + AG_NODES-1)/AG_NODES;
  int nrmWaves = (N + NRM_NPW-1)/NRM_NPW;
  int nrmBlocks = (nrmWaves+3)/4;

  for (int i=0; i<L; ++i) {
    float* gsum_i = gsum + (size_t)i*GG*DD;
    float* gsq_i  = gsq  + (size_t)i*GG*DD;
    int last = (i==L-1) ? 1 : 0;
    gather_kernel<<<gthBlocks, 256, 0, stream>>>(hb, rp_f, col_f, rp_b, col_b, sbufb, N);
    gemm_kernel<<<agBlocks, 512, 0, stream>>>(hb, sbufb,
                                              W_l+(size_t)i*DD*DD, W_r+(size_t)i*DD*DD,
                                              bias+(size_t)i*DD, batch, tb, gsum_i, gsq_i, N);
    norm2_kernel<<<nrmBlocks, 256, 0, stream>>>(tb, gsum_i, gsq_i, cnt, batch,
                                                gn_w+(size_t)i*DD, gn_b+(size_t)i*DD,
                                                gn_ms+(size_t)i*DD,
                                                hb, pout, (i>=2)?1:0, last, N);
  }
  finalize_kernel<<<16, 256, 0, stream>>>(pout, cnt, (float*)d_out);
}